// Round 4
// baseline (352.821 us; speedup 1.0000x reference)
//
#include <hip/hip_runtime.h>
#include <stdint.h>

// Problem constants
#define B_   2
#define T_   4096
#define C_   768
#define H_   12
#define D_   64
#define BH_  24      // B_*H_
#define M_   8192    // B_*T_
#define K_   768
#define N1_  2304    // 3*C_

#define NEG_BIG (-1.0e30f)

typedef short bf16x8 __attribute__((ext_vector_type(8)));
typedef float f32x4  __attribute__((ext_vector_type(4)));
typedef float f32x16 __attribute__((ext_vector_type(16)));
typedef uint32_t u32x4 __attribute__((ext_vector_type(4)));

typedef const __attribute__((address_space(1))) void* as1cv;
typedef __attribute__((address_space(3))) void*       as3v;

__device__ __forceinline__ void gload_lds16(const void* g, void* l) {
  __builtin_amdgcn_global_load_lds((as1cv)g, (as3v)l, 16, 0, 0);
}

// fp32 -> bf16 bits, round-to-nearest-even
__device__ __forceinline__ unsigned short f2bf(float f) {
  uint32_t x = __builtin_bit_cast(uint32_t, f);
  uint32_t r = (x + 0x7fffu + ((x >> 16) & 1u)) >> 16;
  return (unsigned short)r;
}

__device__ __forceinline__ uint32_t pk2bf(float lo, float hi) {
  return ((uint32_t)f2bf(hi) << 16) | (uint32_t)f2bf(lo);
}

// raw barrier + counted waits (m201 idiom): compiler must NOT insert vmcnt(0)
__device__ __forceinline__ void bar() { asm volatile("s_barrier" ::: "memory"); }
__device__ __forceinline__ void wait_vm8() { asm volatile("s_waitcnt vmcnt(8)" ::: "memory"); }
__device__ __forceinline__ void wait_vm0() { asm volatile("s_waitcnt vmcnt(0)" ::: "memory"); }

// ---------------------------------------------------------------- cast x -> bf16
__global__ void cast_kernel(const float* __restrict__ in, unsigned short* __restrict__ out, int n4) {
  int idx = blockIdx.x * blockDim.x + threadIdx.x;
  int stride = gridDim.x * blockDim.x;
  for (int i = idx; i < n4; i += stride) {
    float4 v = reinterpret_cast<const float4*>(in)[i];
    ushort4 o;
    o.x = f2bf(v.x); o.y = f2bf(v.y); o.z = f2bf(v.z); o.w = f2bf(v.w);
    reinterpret_cast<ushort4*>(out)[i] = o;
  }
}

// ------------------------------------------- transpose + cast: in[K][N] -> out[N][K] bf16
__global__ void transpose_cast(const float* __restrict__ in, unsigned short* __restrict__ out,
                               int K, int N) {
  __shared__ float tile[32][33];
  const int tx = threadIdx.x, ty = threadIdx.y;
  const int n = blockIdx.x * 32 + tx;
  #pragma unroll
  for (int r = 0; r < 4; ++r) {
    int k = blockIdx.y * 32 + ty + r * 8;
    tile[ty + r * 8][tx] = in[(size_t)k * N + n];
  }
  __syncthreads();
  const int k = blockIdx.y * 32 + tx;
  #pragma unroll
  for (int r = 0; r < 4; ++r) {
    int nn = blockIdx.x * 32 + ty + r * 8;
    out[(size_t)nn * K + k] = f2bf(tile[tx][ty + r * 8]);
  }
}

// ---------------------------------------------------------------- GEMM (m97-like)
// C[M][N] = A[M][768] * BT[N][768]^T + bias
// MODE 0: scatter epilogue -> Q (x0.125), K as [BH][T][D], V transposed to [BH][D][T], bf16
// MODE 1: plain fp32 store to fo[M][768]
template <int MODE>
__global__ __launch_bounds__(256) void gemm_kernel(
    const unsigned short* __restrict__ A, const unsigned short* __restrict__ BT,
    const float* __restrict__ bias,
    unsigned short* __restrict__ o0, unsigned short* __restrict__ o1,
    unsigned short* __restrict__ o2, float* __restrict__ fo) {
  __shared__ __align__(16) unsigned short Al[128 * 32];
  __shared__ __align__(16) unsigned short Bl[128 * 32];
  const int tid = threadIdx.x;
  const int w = tid >> 6, lane = tid & 63;
  const int g = lane >> 4, c16 = lane & 15;
  const int wr = w >> 1, wc = w & 1;
  const int m0 = blockIdx.x * 128, n0 = blockIdx.y * 128;

  f32x4 acc[4][4] = {};

  for (int k0 = 0; k0 < K_; k0 += 32) {
    __syncthreads();
    #pragma unroll
    for (int q = 0; q < 2; ++q) {
      const int ch = (w * 2 + q) * 64 + lane;     // 0..511
      const int row = ch >> 2, kb = ch & 3;       // 128 rows x 4 x 16B
      gload_lds16(A  + (size_t)(m0 + row) * K_ + k0 + kb * 8, &Al[(w * 2 + q) * 512]);
      gload_lds16(BT + (size_t)(n0 + row) * K_ + k0 + kb * 8, &Bl[(w * 2 + q) * 512]);
    }
    __syncthreads();
    bf16x8 af[4], bfr[4];
    #pragma unroll
    for (int i = 0; i < 4; ++i) {
      af[i]  = *reinterpret_cast<const bf16x8*>(&Al[(wr * 64 + i * 16 + c16) * 32 + g * 8]);
      bfr[i] = *reinterpret_cast<const bf16x8*>(&Bl[(wc * 64 + i * 16 + c16) * 32 + g * 8]);
    }
    #pragma unroll
    for (int i = 0; i < 4; ++i)
      #pragma unroll
      for (int j = 0; j < 4; ++j)
        acc[i][j] = __builtin_amdgcn_mfma_f32_16x16x32_bf16(af[i], bfr[j], acc[i][j], 0, 0, 0);
  }

  const int which = (MODE == 0) ? (n0 / 768) : 0;
  #pragma unroll
  for (int i = 0; i < 4; ++i) {
    const int mbase = m0 + wr * 64 + i * 16 + g * 4;
    #pragma unroll
    for (int j2 = 0; j2 < 4; ++j2) {
      const int n = n0 + wc * 64 + j2 * 16 + c16;
      const float bv = bias[n];
      #pragma unroll
      for (int j = 0; j < 4; ++j) {
        float v = acc[i][j2][j] + bv;
        const int mm = mbase + j;
        if constexpr (MODE == 0) {
          const int cc = n - which * 768;
          const int hh = cc >> 6, dd = cc & 63;
          const int bb = mm >> 12, tt = mm & 4095;
          const size_t bh = (size_t)bb * H_ + hh;
          if (which == 0)      o0[(bh * T_ + tt) * D_ + dd] = f2bf(v * 0.125f); // Q pre-scaled
          else if (which == 1) o1[(bh * T_ + tt) * D_ + dd] = f2bf(v);          // K
          else                 o2[(bh * D_ + dd) * T_ + tt] = f2bf(v);          // V^T
        } else {
          fo[(size_t)mm * 768 + n] = v;
        }
      }
    }
  }
}

// ---------------------------------------------------------------- flash attention
// 2 waves x 32 q-rows = 64 q-rows/block, KVBLK=64, 32x32x16 MFMA, grid 64x24.
// Double-buffered K/V staging with counted vmcnt(8) + raw s_barrier (T3 2-phase):
// stage(t+1) is in flight while compute(t) runs; never drain vmcnt to 0 mid-loop.
// Swapped QK^T (mfma(K,Q) -> S^T): lane owns ONE q-row; softmax lane-local.
// PV as Y^T = V^T * P^T. P half-exchange via __shfl_xor(.,32)+select.
__global__ __launch_bounds__(128) void attn_kernel(
    const unsigned short* __restrict__ Qb, const unsigned short* __restrict__ Kb,
    const unsigned short* __restrict__ Vt, unsigned short* __restrict__ Yb) {
  // 2 buffers x (K 8KB + V 8KB) = 32KB
  __shared__ __align__(16) unsigned short KV[16384];

  const int tid = threadIdx.x;
  const int w = tid >> 6, lane = tid & 63;
  const int q31 = lane & 31, hi = lane >> 5;
  const int bh = blockIdx.y;
  const int bb = bh / H_, hh = bh % H_;
  const int jt = (int)gridDim.x - 1 - (int)blockIdx.x;  // longest blocks first
  const int qb0 = jt * 64;
  const int q0 = qb0 + w * 32;
  const int qg = q0 + q31;  // this lane's q row

  const size_t hoff = (size_t)bh * T_ * D_;
  const unsigned short* Qh = Qb + hoff;
  const unsigned short* Kh = Kb + hoff;
  const unsigned short* Vh = Vt + hoff;  // [64][4096]

  // Q fragments: B-operand, col = q31, k = s*16 + hi*8 + e
  bf16x8 qf[4];
  #pragma unroll
  for (int s = 0; s < 4; ++s)
    qf[s] = *reinterpret_cast<const bf16x8*>(&Qh[(size_t)qg * D_ + s * 16 + hi * 8]);

  // staging: 8 calls x 128 threads x 16B = 16KB (K rows 16c+krow0, V rows 16c+krow0)
  const int krow0 = tid >> 3;                 // 0..15
  const int cg = (tid & 7) ^ (krow0 & 7);     // pre-swizzled source chunk

  // frag read addrs (bytes): row q31, chunk c = 2s+hi, swizzle ^(q31&7)
  int pa[4];
  #pragma unroll
  for (int s = 0; s < 4; ++s)
    pa[s] = q31 * 128 + (((2 * s + hi) ^ (q31 & 7)) << 4);

  float mrun = NEG_BIG, lrun = 0.f;
  f32x16 y0 = {}, y1 = {};

  const int nt = jt + 1;  // kv tiles 0..jt

  // stage(t): K -> buf[t&1][0,8KB), V^T -> buf[t&1][8KB,16KB)
  auto stage = [&](int t) {
    const int kv0 = t << 6;
    const int b = (t & 1) << 13;  // ushort offset: 8192 per buffer
    #pragma unroll
    for (int c = 0; c < 4; ++c)
      gload_lds16(Kh + (size_t)(kv0 + 16 * c + krow0) * D_ + cg * 8,
                  &KV[b + c * 1024 + w * 512]);
    #pragma unroll
    for (int c = 0; c < 4; ++c)
      gload_lds16(Vh + (size_t)(16 * c + krow0) * T_ + kv0 + cg * 8,
                  &KV[b + 4096 + c * 1024 + w * 512]);
  };

  stage(0);  // prologue: 8 loads in flight

  for (int it = 0; it < nt; ++it) {
    const int kv0 = it << 6;
    if (it + 1 < nt) { stage(it + 1); wait_vm8(); }  // next tile flies during compute
    else             { wait_vm0(); }
    bar();  // buf[it&1] ready for all waves

    const char* lds = (const char*)&KV[0] + ((it & 1) << 14);  // byte offset 16384

    // ---- S^T = K * Q^T : two 32x32 half-tiles (kv 0..31, 32..63)
    f32x16 s0 = {}, s1 = {};
    #pragma unroll
    for (int s = 0; s < 4; ++s) {
      bf16x8 kf0 = *reinterpret_cast<const bf16x8*>(lds + pa[s]);
      s0 = __builtin_amdgcn_mfma_f32_32x32x16_bf16(kf0, qf[s], s0, 0, 0, 0);
    }
    #pragma unroll
    for (int s = 0; s < 4; ++s) {
      bf16x8 kf1 = *reinterpret_cast<const bf16x8*>(lds + pa[s] + 4096);
      s1 = __builtin_amdgcn_mfma_f32_32x32x16_bf16(kf1, qf[s], s1, 0, 0, 0);
    }

    // ---- causal mask (finite sentinel); kv_local = (r&3)+8*(r>>2)+4*hi
    if (kv0 + 63 > q0) {
      #pragma unroll
      for (int r = 0; r < 16; ++r) {
        const int kvl = (r & 3) + 8 * (r >> 2) + 4 * hi;
        s0[r] = (kv0 + kvl > qg)      ? NEG_BIG : s0[r];
        s1[r] = (kv0 + 32 + kvl > qg) ? NEG_BIG : s1[r];
      }
    }

    // ---- column max: in-lane tree + cross-half merge (shfl_xor 32)
    float a[16];
    #pragma unroll
    for (int r = 0; r < 8; ++r) a[r] = fmaxf(s0[2 * r], s0[2 * r + 1]);
    #pragma unroll
    for (int r = 0; r < 8; ++r) a[8 + r] = fmaxf(s1[2 * r], s1[2 * r + 1]);
    #pragma unroll
    for (int st = 8; st > 0; st >>= 1)
      #pragma unroll
      for (int r = 0; r < 16; ++r) if (r < st) a[r] = fmaxf(a[r], a[r + st]);
    float tmax = a[0];
    tmax = fmaxf(tmax, __shfl_xor(tmax, 32));

    // ---- online rescale (every tile; lane-local)
    const float mnew = fmaxf(mrun, tmax);
    const float alpha = __expf(mrun - mnew);  // exp(-1e30) = 0 on first tile
    mrun = mnew;
    lrun *= alpha;
    #pragma unroll
    for (int r = 0; r < 16; ++r) { y0[r] *= alpha; y1[r] *= alpha; }

    // ---- P = exp(S - m)
    #pragma unroll
    for (int r = 0; r < 16; ++r) {
      s0[r] = __expf(s0[r] - mrun);
      s1[r] = __expf(s1[r] - mrun);
    }

    // ---- column sum: tree + merge
    #pragma unroll
    for (int r = 0; r < 8; ++r) a[r] = s0[2 * r] + s0[2 * r + 1];
    #pragma unroll
    for (int r = 0; r < 8; ++r) a[8 + r] = s1[2 * r] + s1[2 * r + 1];
    #pragma unroll
    for (int st = 8; st > 0; st >>= 1)
      #pragma unroll
      for (int r = 0; r < 16; ++r) if (r < st) a[r] = a[r] + a[r + st];
    float rsum = a[0];
    rsum += __shfl_xor(rsum, 32);
    lrun += rsum;

    // ---- P^T B-fragments via pk2bf + shfl_xor(32) + select.
    bf16x8 pf[4];
#define MK_PF(KS, SH, GA, HA)                                                 \
    {                                                                         \
      uint32_t g0 = pk2bf(SH[(GA)*4 + 0], SH[(GA)*4 + 1]);                    \
      uint32_t g1 = pk2bf(SH[(GA)*4 + 2], SH[(GA)*4 + 3]);                    \
      uint32_t h0 = pk2bf(SH[(HA)*4 + 0], SH[(HA)*4 + 1]);                    \
      uint32_t h1 = pk2bf(SH[(HA)*4 + 2], SH[(HA)*4 + 3]);                    \
      uint32_t sg0 = (uint32_t)__shfl_xor((int)g0, 32);                       \
      uint32_t sg1 = (uint32_t)__shfl_xor((int)g1, 32);                       \
      uint32_t sh0 = (uint32_t)__shfl_xor((int)h0, 32);                       \
      uint32_t sh1 = (uint32_t)__shfl_xor((int)h1, 32);                       \
      u32x4 t;                                                                \
      t[0] = hi ? sh0 : g0;                                                   \
      t[1] = hi ? sh1 : g1;                                                   \
      t[2] = hi ? h0 : sg0;                                                   \
      t[3] = hi ? h1 : sg1;                                                   \
      pf[KS] = __builtin_bit_cast(bf16x8, t);                                 \
    }
    MK_PF(0, s0, 0, 1)
    MK_PF(1, s0, 2, 3)
    MK_PF(2, s1, 0, 1)
    MK_PF(3, s1, 2, 3)
#undef MK_PF

    // ---- PV: Y^T += V^T * P^T  (A = V^T frag rows d, B = pf)
    #pragma unroll
    for (int ks = 0; ks < 4; ++ks) {
      bf16x8 vf0 = *reinterpret_cast<const bf16x8*>(lds + pa[ks] + 8192);
      y0 = __builtin_amdgcn_mfma_f32_32x32x16_bf16(vf0, pf[ks], y0, 0, 0, 0);
    }
    #pragma unroll
    for (int ks = 0; ks < 4; ++ks) {
      bf16x8 vf1 = *reinterpret_cast<const bf16x8*>(lds + pa[ks] + 12288);
      y1 = __builtin_amdgcn_mfma_f32_32x32x16_bf16(vf1, pf[ks], y1, 0, 0, 0);
    }

    bar();  // all waves done reading buf[it&1]; next iter may overwrite
  }

  // ---- epilogue: y/l, store row qg (lane-local). y reg r -> d = (r&3)+8*(r>>2)+4*hi
  const float inv = 1.f / lrun;
  const size_t ro = ((size_t)bb * T_ + qg) * C_ + hh * D_;
  #pragma unroll
  for (int q2 = 0; q2 < 4; ++q2) {
    {
      uint32_t w0 = pk2bf(y0[q2 * 4 + 0] * inv, y0[q2 * 4 + 1] * inv);
      uint32_t w1 = pk2bf(y0[q2 * 4 + 2] * inv, y0[q2 * 4 + 3] * inv);
      uint2 pr = {w0, w1};
      *reinterpret_cast<uint2*>(&Yb[ro + q2 * 8 + hi * 4]) = pr;
    }
    {
      uint32_t w0 = pk2bf(y1[q2 * 4 + 0] * inv, y1[q2 * 4 + 1] * inv);
      uint32_t w1 = pk2bf(y1[q2 * 4 + 2] * inv, y1[q2 * 4 + 3] * inv);
      uint2 pr = {w0, w1};
      *reinterpret_cast<uint2*>(&Yb[ro + 32 + q2 * 8 + hi * 4]) = pr;
    }
  }
}

// ---------------------------------------------------------------- launch
extern "C" void kernel_launch(void* const* d_in, const int* in_sizes, int n_in,
                              void* d_out, int out_size, void* d_ws, size_t ws_size,
                              hipStream_t stream) {
  const float* x      = (const float*)d_in[0];
  const float* w_attn = (const float*)d_in[1];
  const float* b_attn = (const float*)d_in[2];
  const float* w_proj = (const float*)d_in[3];
  const float* b_proj = (const float*)d_in[4];
  float* out = (float*)d_out;

  char* ws = (char*)d_ws;
  size_t off = 0;
  auto alloc = [&](size_t bytes) -> void* {
    void* p = ws + off;
    off += (bytes + 255) & ~(size_t)255;
    return p;
  };
  unsigned short* xb  = (unsigned short*)alloc((size_t)M_ * K_ * 2);       // x bf16
  unsigned short* waT = (unsigned short*)alloc((size_t)N1_ * K_ * 2);      // w_attn^T bf16
  unsigned short* wpT = (unsigned short*)alloc((size_t)C_ * K_ * 2);       // w_proj^T bf16
  unsigned short* Qb  = (unsigned short*)alloc((size_t)BH_ * T_ * D_ * 2); // [BH][T][D]
  unsigned short* Kb  = (unsigned short*)alloc((size_t)BH_ * T_ * D_ * 2);
  unsigned short* Vt  = (unsigned short*)alloc((size_t)BH_ * D_ * T_ * 2); // [BH][D][T]
  unsigned short* Yb  = (unsigned short*)alloc((size_t)M_ * C_ * 2);       // attn out bf16

  cast_kernel<<<1024, 256, 0, stream>>>(x, xb, M_ * K_ / 4);
  transpose_cast<<<dim3(N1_ / 32, K_ / 32), dim3(32, 8), 0, stream>>>(w_attn, waT, K_, N1_);
  transpose_cast<<<dim3(C_ / 32, K_ / 32), dim3(32, 8), 0, stream>>>(w_proj, wpT, K_, C_);

  gemm_kernel<0><<<dim3(M_ / 128, N1_ / 128), 256, 0, stream>>>(
      xb, waT, b_attn, Qb, Kb, Vt, nullptr);

  attn_kernel<<<dim3(T_ / 64, BH_), 128, 0, stream>>>(Qb, Kb, Vt, Yb);

  gemm_kernel<1><<<dim3(M_ / 128, C_ / 128), 256, 0, stream>>>(
      Yb, wpT, b_proj, nullptr, nullptr, nullptr, out);
}

// Round 5
// 286.685 us; speedup vs baseline: 1.2307x; 1.2307x over previous
//
#include <hip/hip_runtime.h>
#include <stdint.h>

// Problem constants
#define B_   2
#define T_   4096
#define C_   768
#define H_   12
#define D_   64
#define BH_  24      // B_*H_
#define M_   8192    // B_*T_
#define K_   768
#define N1_  2304    // 3*C_

#define NEG_BIG (-1.0e30f)

typedef short bf16x8 __attribute__((ext_vector_type(8)));
typedef float f32x4  __attribute__((ext_vector_type(4)));
typedef float f32x16 __attribute__((ext_vector_type(16)));
typedef uint32_t u32x4 __attribute__((ext_vector_type(4)));

typedef const __attribute__((address_space(1))) void* as1cv;
typedef __attribute__((address_space(3))) void*       as3v;

__device__ __forceinline__ void gload_lds16(const void* g, void* l) {
  __builtin_amdgcn_global_load_lds((as1cv)g, (as3v)l, 16, 0, 0);
}

// fp32 -> bf16 bits, round-to-nearest-even
__device__ __forceinline__ unsigned short f2bf(float f) {
  uint32_t x = __builtin_bit_cast(uint32_t, f);
  uint32_t r = (x + 0x7fffu + ((x >> 16) & 1u)) >> 16;
  return (unsigned short)r;
}

__device__ __forceinline__ uint32_t pk2bf(float lo, float hi) {
  return ((uint32_t)f2bf(hi) << 16) | (uint32_t)f2bf(lo);
}

// ---------------------------------------------------------------- cast x -> bf16
__global__ void cast_kernel(const float* __restrict__ in, unsigned short* __restrict__ out, int n4) {
  int idx = blockIdx.x * blockDim.x + threadIdx.x;
  int stride = gridDim.x * blockDim.x;
  for (int i = idx; i < n4; i += stride) {
    float4 v = reinterpret_cast<const float4*>(in)[i];
    ushort4 o;
    o.x = f2bf(v.x); o.y = f2bf(v.y); o.z = f2bf(v.z); o.w = f2bf(v.w);
    reinterpret_cast<ushort4*>(out)[i] = o;
  }
}

// ------------------------------------------- transpose + cast: in[K][N] -> out[N][K] bf16
__global__ void transpose_cast(const float* __restrict__ in, unsigned short* __restrict__ out,
                               int K, int N) {
  __shared__ float tile[32][33];
  const int tx = threadIdx.x, ty = threadIdx.y;
  const int n = blockIdx.x * 32 + tx;
  #pragma unroll
  for (int r = 0; r < 4; ++r) {
    int k = blockIdx.y * 32 + ty + r * 8;
    tile[ty + r * 8][tx] = in[(size_t)k * N + n];
  }
  __syncthreads();
  const int k = blockIdx.y * 32 + tx;
  #pragma unroll
  for (int r = 0; r < 4; ++r) {
    int nn = blockIdx.x * 32 + ty + r * 8;
    out[(size_t)nn * K + k] = f2bf(tile[tx][ty + r * 8]);
  }
}

// ---------------------------------------------------------------- GEMM (m97-like)
// C[M][N] = A[M][768] * BT[N][768]^T + bias
// MODE 0: scatter epilogue -> Q (x0.125), K as [BH][T][D], V transposed to [BH][D][T], bf16
// MODE 1: plain fp32 store to fo[M][768]
template <int MODE>
__global__ __launch_bounds__(256) void gemm_kernel(
    const unsigned short* __restrict__ A, const unsigned short* __restrict__ BT,
    const float* __restrict__ bias,
    unsigned short* __restrict__ o0, unsigned short* __restrict__ o1,
    unsigned short* __restrict__ o2, float* __restrict__ fo) {
  __shared__ __align__(16) unsigned short Al[128 * 32];
  __shared__ __align__(16) unsigned short Bl[128 * 32];
  const int tid = threadIdx.x;
  const int w = tid >> 6, lane = tid & 63;
  const int g = lane >> 4, c16 = lane & 15;
  const int wr = w >> 1, wc = w & 1;
  const int m0 = blockIdx.x * 128, n0 = blockIdx.y * 128;

  f32x4 acc[4][4] = {};

  for (int k0 = 0; k0 < K_; k0 += 32) {
    __syncthreads();
    #pragma unroll
    for (int q = 0; q < 2; ++q) {
      const int ch = (w * 2 + q) * 64 + lane;     // 0..511
      const int row = ch >> 2, kb = ch & 3;       // 128 rows x 4 x 16B
      gload_lds16(A  + (size_t)(m0 + row) * K_ + k0 + kb * 8, &Al[(w * 2 + q) * 512]);
      gload_lds16(BT + (size_t)(n0 + row) * K_ + k0 + kb * 8, &Bl[(w * 2 + q) * 512]);
    }
    __syncthreads();
    bf16x8 af[4], bfr[4];
    #pragma unroll
    for (int i = 0; i < 4; ++i) {
      af[i]  = *reinterpret_cast<const bf16x8*>(&Al[(wr * 64 + i * 16 + c16) * 32 + g * 8]);
      bfr[i] = *reinterpret_cast<const bf16x8*>(&Bl[(wc * 64 + i * 16 + c16) * 32 + g * 8]);
    }
    #pragma unroll
    for (int i = 0; i < 4; ++i)
      #pragma unroll
      for (int j = 0; j < 4; ++j)
        acc[i][j] = __builtin_amdgcn_mfma_f32_16x16x32_bf16(af[i], bfr[j], acc[i][j], 0, 0, 0);
  }

  const int which = (MODE == 0) ? (n0 / 768) : 0;
  #pragma unroll
  for (int i = 0; i < 4; ++i) {
    const int mbase = m0 + wr * 64 + i * 16 + g * 4;
    #pragma unroll
    for (int j2 = 0; j2 < 4; ++j2) {
      const int n = n0 + wc * 64 + j2 * 16 + c16;
      const float bv = bias[n];
      #pragma unroll
      for (int j = 0; j < 4; ++j) {
        float v = acc[i][j2][j] + bv;
        const int mm = mbase + j;
        if constexpr (MODE == 0) {
          const int cc = n - which * 768;
          const int hh = cc >> 6, dd = cc & 63;
          const int bb = mm >> 12, tt = mm & 4095;
          const size_t bh = (size_t)bb * H_ + hh;
          if (which == 0)      o0[(bh * T_ + tt) * D_ + dd] = f2bf(v * 0.125f); // Q pre-scaled
          else if (which == 1) o1[(bh * T_ + tt) * D_ + dd] = f2bf(v);          // K
          else                 o2[(bh * D_ + dd) * T_ + tt] = f2bf(v);          // V^T
        } else {
          fo[(size_t)mm * 768 + n] = v;
        }
      }
    }
  }
}

// ---------------------------------------------------------------- flash attention
// 1 wave per block, 32 q-rows, KVBLK=64, 32x32x16 MFMA, NO LDS / NO barriers.
// Every MFMA fragment is a contiguous 16B global load per lane (L2-served):
//   K-frag  lane l: K[kv0 + (l&31)][s*16 + (l>>5)*8 .. +8]
//   V-frag  lane l: V^T[d = (l&31) (+32)][kv0 + ks*16 + (l>>5)*8 .. +8]
// Swapped QK^T (mfma(K,Q) -> S^T): lane owns ONE q-row; softmax lane-local.
// bh->XCD locality: bid = strip*24 + bh, so bid%8 == bh%8 (24%8==0) and each
// XCD's L2 keeps its 3 heads' K/V (3MB < 4MB). Longest strips dispatch first.
__global__ __launch_bounds__(64, 3) void attn_kernel(
    const unsigned short* __restrict__ Qb, const unsigned short* __restrict__ Kb,
    const unsigned short* __restrict__ Vt, unsigned short* __restrict__ Yb) {
  const int lane = threadIdx.x;
  const int q31 = lane & 31, hi = lane >> 5;
  const int bid = blockIdx.x;
  const int bh = bid % BH_;
  const int strip = (T_ / 32 - 1) - bid / BH_;  // 127..0, longest first
  const int q0 = strip * 32;
  const int qg = q0 + q31;  // this lane's q row

  const int bb = bh / H_, hh = bh % H_;
  const size_t hoff = (size_t)bh * T_ * D_;
  const unsigned short* Qh = Qb + hoff;
  const unsigned short* Kh = Kb + hoff;
  const unsigned short* Vh = Vt + hoff;  // [64][4096]

  // Q fragments: B-operand, col = q31, k = s*16 + hi*8 + e
  bf16x8 qf[4];
  #pragma unroll
  for (int s = 0; s < 4; ++s)
    qf[s] = *reinterpret_cast<const bf16x8*>(&Qh[(size_t)qg * D_ + s * 16 + hi * 8]);

  // per-lane fragment base pointers
  const unsigned short* Krow  = Kh + (size_t)q31 * D_ + hi * 8;         // + kv0*D_ per tile
  const unsigned short* VrowA = Vh + (size_t)q31 * T_ + hi * 8;         // d = q31
  const unsigned short* VrowB = Vh + (size_t)(32 + q31) * T_ + hi * 8;  // d = 32+q31

  float mrun = NEG_BIG, lrun = 0.f;
  f32x16 y0 = {}, y1 = {};

  const int nt = ((q0 + 31) >> 6) + 1;  // kv tiles 0..floor((q0+31)/64)

  for (int it = 0; it < nt; ++it) {
    const int kv0 = it << 6;

    // ---- S^T = K * Q^T : two 32x32 half-tiles (kv 0..31, 32..63)
    const unsigned short* kA = Krow + (size_t)kv0 * D_;
    f32x16 s0 = {}, s1 = {};
    #pragma unroll
    for (int s = 0; s < 4; ++s) {
      bf16x8 kf = *reinterpret_cast<const bf16x8*>(kA + s * 16);
      s0 = __builtin_amdgcn_mfma_f32_32x32x16_bf16(kf, qf[s], s0, 0, 0, 0);
    }
    #pragma unroll
    for (int s = 0; s < 4; ++s) {
      bf16x8 kf = *reinterpret_cast<const bf16x8*>(kA + 32 * D_ + s * 16);
      s1 = __builtin_amdgcn_mfma_f32_32x32x16_bf16(kf, qf[s], s1, 0, 0, 0);
    }

    // ---- V fragments issued early; consumed after softmax (latency hidden)
    bf16x8 vfA[4], vfB[4];
    #pragma unroll
    for (int ks = 0; ks < 4; ++ks) {
      vfA[ks] = *reinterpret_cast<const bf16x8*>(VrowA + kv0 + ks * 16);
      vfB[ks] = *reinterpret_cast<const bf16x8*>(VrowB + kv0 + ks * 16);
    }

    // ---- causal mask (finite sentinel); kv_local = (r&3)+8*(r>>2)+4*hi
    if (kv0 + 63 > q0) {
      #pragma unroll
      for (int r = 0; r < 16; ++r) {
        const int kvl = (r & 3) + 8 * (r >> 2) + 4 * hi;
        s0[r] = (kv0 + kvl > qg)      ? NEG_BIG : s0[r];
        s1[r] = (kv0 + 32 + kvl > qg) ? NEG_BIG : s1[r];
      }
    }

    // ---- column max: in-lane tree + cross-half merge (shfl_xor 32)
    float a[16];
    #pragma unroll
    for (int r = 0; r < 8; ++r) a[r] = fmaxf(s0[2 * r], s0[2 * r + 1]);
    #pragma unroll
    for (int r = 0; r < 8; ++r) a[8 + r] = fmaxf(s1[2 * r], s1[2 * r + 1]);
    #pragma unroll
    for (int st = 8; st > 0; st >>= 1)
      #pragma unroll
      for (int r = 0; r < 16; ++r) if (r < st) a[r] = fmaxf(a[r], a[r + st]);
    float tmax = a[0];
    tmax = fmaxf(tmax, __shfl_xor(tmax, 32));

    // ---- online rescale (every tile; lane-local)
    const float mnew = fmaxf(mrun, tmax);
    const float alpha = __expf(mrun - mnew);  // exp(-1e30) = 0 on first tile
    mrun = mnew;
    lrun *= alpha;
    #pragma unroll
    for (int r = 0; r < 16; ++r) { y0[r] *= alpha; y1[r] *= alpha; }

    // ---- P = exp(S - m)
    #pragma unroll
    for (int r = 0; r < 16; ++r) {
      s0[r] = __expf(s0[r] - mrun);
      s1[r] = __expf(s1[r] - mrun);
    }

    // ---- column sum: tree + merge
    #pragma unroll
    for (int r = 0; r < 8; ++r) a[r] = s0[2 * r] + s0[2 * r + 1];
    #pragma unroll
    for (int r = 0; r < 8; ++r) a[8 + r] = s1[2 * r] + s1[2 * r + 1];
    #pragma unroll
    for (int st = 8; st > 0; st >>= 1)
      #pragma unroll
      for (int r = 0; r < 16; ++r) if (r < st) a[r] = a[r] + a[r + st];
    float rsum = a[0];
    rsum += __shfl_xor(rsum, 32);
    lrun += rsum;

    // ---- P^T B-fragments via pk2bf + shfl_xor(32) + select.
    bf16x8 pf[4];
#define MK_PF(KS, SH, GA, HA)                                                 \
    {                                                                         \
      uint32_t g0 = pk2bf(SH[(GA)*4 + 0], SH[(GA)*4 + 1]);                    \
      uint32_t g1 = pk2bf(SH[(GA)*4 + 2], SH[(GA)*4 + 3]);                    \
      uint32_t h0 = pk2bf(SH[(HA)*4 + 0], SH[(HA)*4 + 1]);                    \
      uint32_t h1 = pk2bf(SH[(HA)*4 + 2], SH[(HA)*4 + 3]);                    \
      uint32_t sg0 = (uint32_t)__shfl_xor((int)g0, 32);                       \
      uint32_t sg1 = (uint32_t)__shfl_xor((int)g1, 32);                       \
      uint32_t sh0 = (uint32_t)__shfl_xor((int)h0, 32);                       \
      uint32_t sh1 = (uint32_t)__shfl_xor((int)h1, 32);                       \
      u32x4 t;                                                                \
      t[0] = hi ? sh0 : g0;                                                   \
      t[1] = hi ? sh1 : g1;                                                   \
      t[2] = hi ? h0 : sg0;                                                   \
      t[3] = hi ? h1 : sg1;                                                   \
      pf[KS] = __builtin_bit_cast(bf16x8, t);                                 \
    }
    MK_PF(0, s0, 0, 1)
    MK_PF(1, s0, 2, 3)
    MK_PF(2, s1, 0, 1)
    MK_PF(3, s1, 2, 3)
#undef MK_PF

    // ---- PV: Y^T += V^T * P^T  (A = V^T frag rows d / d+32, B = pf)
    #pragma unroll
    for (int ks = 0; ks < 4; ++ks)
      y0 = __builtin_amdgcn_mfma_f32_32x32x16_bf16(vfA[ks], pf[ks], y0, 0, 0, 0);
    #pragma unroll
    for (int ks = 0; ks < 4; ++ks)
      y1 = __builtin_amdgcn_mfma_f32_32x32x16_bf16(vfB[ks], pf[ks], y1, 0, 0, 0);
  }

  // ---- epilogue: y/l, store row qg (lane-local). y reg r -> d = (r&3)+8*(r>>2)+4*hi
  const float inv = 1.f / lrun;
  const size_t ro = ((size_t)bb * T_ + qg) * C_ + hh * D_;
  #pragma unroll
  for (int q2 = 0; q2 < 4; ++q2) {
    {
      uint32_t w0 = pk2bf(y0[q2 * 4 + 0] * inv, y0[q2 * 4 + 1] * inv);
      uint32_t w1 = pk2bf(y0[q2 * 4 + 2] * inv, y0[q2 * 4 + 3] * inv);
      uint2 pr = {w0, w1};
      *reinterpret_cast<uint2*>(&Yb[ro + q2 * 8 + hi * 4]) = pr;
    }
    {
      uint32_t w0 = pk2bf(y1[q2 * 4 + 0] * inv, y1[q2 * 4 + 1] * inv);
      uint32_t w1 = pk2bf(y1[q2 * 4 + 2] * inv, y1[q2 * 4 + 3] * inv);
      uint2 pr = {w0, w1};
      *reinterpret_cast<uint2*>(&Yb[ro + 32 + q2 * 8 + hi * 4]) = pr;
    }
  }
}

// ---------------------------------------------------------------- launch
extern "C" void kernel_launch(void* const* d_in, const int* in_sizes, int n_in,
                              void* d_out, int out_size, void* d_ws, size_t ws_size,
                              hipStream_t stream) {
  const float* x      = (const float*)d_in[0];
  const float* w_attn = (const float*)d_in[1];
  const float* b_attn = (const float*)d_in[2];
  const float* w_proj = (const float*)d_in[3];
  const float* b_proj = (const float*)d_in[4];
  float* out = (float*)d_out;

  char* ws = (char*)d_ws;
  size_t off = 0;
  auto alloc = [&](size_t bytes) -> void* {
    void* p = ws + off;
    off += (bytes + 255) & ~(size_t)255;
    return p;
  };
  unsigned short* xb  = (unsigned short*)alloc((size_t)M_ * K_ * 2);       // x bf16
  unsigned short* waT = (unsigned short*)alloc((size_t)N1_ * K_ * 2);      // w_attn^T bf16
  unsigned short* wpT = (unsigned short*)alloc((size_t)C_ * K_ * 2);       // w_proj^T bf16
  unsigned short* Qb  = (unsigned short*)alloc((size_t)BH_ * T_ * D_ * 2); // [BH][T][D]
  unsigned short* Kb  = (unsigned short*)alloc((size_t)BH_ * T_ * D_ * 2);
  unsigned short* Vt  = (unsigned short*)alloc((size_t)BH_ * D_ * T_ * 2); // [BH][D][T]
  unsigned short* Yb  = (unsigned short*)alloc((size_t)M_ * C_ * 2);       // attn out bf16

  cast_kernel<<<1024, 256, 0, stream>>>(x, xb, M_ * K_ / 4);
  transpose_cast<<<dim3(N1_ / 32, K_ / 32), dim3(32, 8), 0, stream>>>(w_attn, waT, K_, N1_);
  transpose_cast<<<dim3(C_ / 32, K_ / 32), dim3(32, 8), 0, stream>>>(w_proj, wpT, K_, C_);

  gemm_kernel<0><<<dim3(M_ / 128, N1_ / 128), 256, 0, stream>>>(
      xb, waT, b_attn, Qb, Kb, Vt, nullptr);

  attn_kernel<<<(T_ / 32) * BH_, 64, 0, stream>>>(Qb, Kb, Vt, Yb);

  gemm_kernel<1><<<dim3(M_ / 128, C_ / 128), 256, 0, stream>>>(
      Yb, wpT, b_proj, nullptr, nullptr, nullptr, out);
}

// Round 7
// 278.090 us; speedup vs baseline: 1.2687x; 1.0309x over previous
//
#include <hip/hip_runtime.h>
#include <stdint.h>

// Problem constants
#define B_   2
#define T_   4096
#define C_   768
#define H_   12
#define D_   64
#define BH_  24      // B_*H_
#define M_   8192    // B_*T_
#define K_   768
#define N1_  2304    // 3*C_

#define NEG_BIG (-1.0e30f)

typedef short bf16x8 __attribute__((ext_vector_type(8)));
typedef float f32x4  __attribute__((ext_vector_type(4)));
typedef float f32x16 __attribute__((ext_vector_type(16)));
typedef uint32_t u32x4 __attribute__((ext_vector_type(4)));

typedef const __attribute__((address_space(1))) void* as1cv;
typedef __attribute__((address_space(3))) void*       as3v;

__device__ __forceinline__ void gload_lds16(const void* g, void* l) {
  __builtin_amdgcn_global_load_lds((as1cv)g, (as3v)l, 16, 0, 0);
}

// fp32 -> bf16 bits, round-to-nearest-even.
// NOTE: v_cvt_pk_bf16_f32 inline-asm is POISONED on this toolchain (R2: NaN,
// R6: absmax 7.4e30 — packed hi-half left unwritten). Use this software path.
__device__ __forceinline__ unsigned short f2bf(float f) {
  uint32_t x = __builtin_bit_cast(uint32_t, f);
  uint32_t r = (x + 0x7fffu + ((x >> 16) & 1u)) >> 16;
  return (unsigned short)r;
}

__device__ __forceinline__ uint32_t pk2bf(float lo, float hi) {
  return ((uint32_t)f2bf(hi) << 16) | (uint32_t)f2bf(lo);
}

// ---------------------------------------------------------------- cast x -> bf16
__global__ void cast_kernel(const float* __restrict__ in, unsigned short* __restrict__ out, int n4) {
  int idx = blockIdx.x * blockDim.x + threadIdx.x;
  int stride = gridDim.x * blockDim.x;
  for (int i = idx; i < n4; i += stride) {
    float4 v = reinterpret_cast<const float4*>(in)[i];
    ushort4 o;
    o.x = f2bf(v.x); o.y = f2bf(v.y); o.z = f2bf(v.z); o.w = f2bf(v.w);
    reinterpret_cast<ushort4*>(out)[i] = o;
  }
}

// ------------------------------------------- transpose + cast: in[K][N] -> out[N][K] bf16
__global__ void transpose_cast(const float* __restrict__ in, unsigned short* __restrict__ out,
                               int K, int N) {
  __shared__ float tile[32][33];
  const int tx = threadIdx.x, ty = threadIdx.y;
  const int n = blockIdx.x * 32 + tx;
  #pragma unroll
  for (int r = 0; r < 4; ++r) {
    int k = blockIdx.y * 32 + ty + r * 8;
    tile[ty + r * 8][tx] = in[(size_t)k * N + n];
  }
  __syncthreads();
  const int k = blockIdx.y * 32 + tx;
  #pragma unroll
  for (int r = 0; r < 4; ++r) {
    int nn = blockIdx.x * 32 + ty + r * 8;
    out[(size_t)nn * K + k] = f2bf(tile[tx][ty + r * 8]);
  }
}

// ---------------------------------------------------------------- GEMM (m97-like)
// C[M][N] = A[M][768] * BT[N][768]^T + bias
// MODE 0: scatter epilogue -> Q (x0.125), K as [BH][T][D], V transposed to [BH][D][T], bf16
// MODE 1: plain fp32 store to fo[M][768]
template <int MODE>
__global__ __launch_bounds__(256) void gemm_kernel(
    const unsigned short* __restrict__ A, const unsigned short* __restrict__ BT,
    const float* __restrict__ bias,
    unsigned short* __restrict__ o0, unsigned short* __restrict__ o1,
    unsigned short* __restrict__ o2, float* __restrict__ fo) {
  __shared__ __align__(16) unsigned short Al[128 * 32];
  __shared__ __align__(16) unsigned short Bl[128 * 32];
  const int tid = threadIdx.x;
  const int w = tid >> 6, lane = tid & 63;
  const int g = lane >> 4, c16 = lane & 15;
  const int wr = w >> 1, wc = w & 1;
  const int m0 = blockIdx.x * 128, n0 = blockIdx.y * 128;

  f32x4 acc[4][4] = {};

  for (int k0 = 0; k0 < K_; k0 += 32) {
    __syncthreads();
    #pragma unroll
    for (int q = 0; q < 2; ++q) {
      const int ch = (w * 2 + q) * 64 + lane;     // 0..511
      const int row = ch >> 2, kb = ch & 3;       // 128 rows x 4 x 16B
      gload_lds16(A  + (size_t)(m0 + row) * K_ + k0 + kb * 8, &Al[(w * 2 + q) * 512]);
      gload_lds16(BT + (size_t)(n0 + row) * K_ + k0 + kb * 8, &Bl[(w * 2 + q) * 512]);
    }
    __syncthreads();
    bf16x8 af[4], bfr[4];
    #pragma unroll
    for (int i = 0; i < 4; ++i) {
      af[i]  = *reinterpret_cast<const bf16x8*>(&Al[(wr * 64 + i * 16 + c16) * 32 + g * 8]);
      bfr[i] = *reinterpret_cast<const bf16x8*>(&Bl[(wc * 64 + i * 16 + c16) * 32 + g * 8]);
    }
    #pragma unroll
    for (int i = 0; i < 4; ++i)
      #pragma unroll
      for (int j = 0; j < 4; ++j)
        acc[i][j] = __builtin_amdgcn_mfma_f32_16x16x32_bf16(af[i], bfr[j], acc[i][j], 0, 0, 0);
  }

  const int which = (MODE == 0) ? (n0 / 768) : 0;
  #pragma unroll
  for (int i = 0; i < 4; ++i) {
    const int mbase = m0 + wr * 64 + i * 16 + g * 4;
    #pragma unroll
    for (int j2 = 0; j2 < 4; ++j2) {
      const int n = n0 + wc * 64 + j2 * 16 + c16;
      const float bv = bias[n];
      #pragma unroll
      for (int j = 0; j < 4; ++j) {
        float v = acc[i][j2][j] + bv;
        const int mm = mbase + j;
        if constexpr (MODE == 0) {
          const int cc = n - which * 768;
          const int hh = cc >> 6, dd = cc & 63;
          const int bb = mm >> 12, tt = mm & 4095;
          const size_t bh = (size_t)bb * H_ + hh;
          if (which == 0)      o0[(bh * T_ + tt) * D_ + dd] = f2bf(v * 0.125f); // Q pre-scaled
          else if (which == 1) o1[(bh * T_ + tt) * D_ + dd] = f2bf(v);          // K
          else                 o2[(bh * D_ + dd) * T_ + tt] = f2bf(v);          // V^T
        } else {
          fo[(size_t)mm * 768 + n] = v;
        }
      }
    }
  }
}

// ---------------------------------------------------------------- flash attention
// 1 wave per block, 32 q-rows, KVBLK=64, 32x32x16 MFMA, no LDS, no barriers.
// Depth-2 register software pipeline: K fragments for tile t+1 prefetched into
// the alternate buffer (kfA/kfB, statically indexed) while tile t computes.
// Issue order per tile: V(t) loads, K(t+1) loads, then QK(t) — the compiler's
// counted vmcnt before QK leaves V(t)+K(t+1) in flight; before PV leaves K(t+1).
// Swapped QK^T (mfma(K,Q) -> S^T): lane owns ONE q-row; softmax lane-local.
// P-pack via verified software pk2bf + shfl_xor(32)+select half-exchange.
__global__ __launch_bounds__(64, 2) void attn_kernel(
    const unsigned short* __restrict__ Qb, const unsigned short* __restrict__ Kb,
    const unsigned short* __restrict__ Vt, unsigned short* __restrict__ Yb) {
  const int lane = threadIdx.x;
  const int q31 = lane & 31, hi = lane >> 5;
  const int bid = blockIdx.x;
  const int bh = bid % BH_;                     // bid%8 == bh%8 -> bh->XCD locality
  const int strip = (T_ / 32 - 1) - bid / BH_;  // 127..0, longest first
  const int q0 = strip * 32;
  const int qg = q0 + q31;  // this lane's q row

  const int bb = bh / H_, hh = bh % H_;
  const size_t hoff = (size_t)bh * T_ * D_;
  const unsigned short* Qh = Qb + hoff;
  const unsigned short* Kh = Kb + hoff;
  const unsigned short* Vh = Vt + hoff;  // [64][4096]

  // Q fragments: B-operand, col = q31, k = s*16 + hi*8 + e
  bf16x8 qf[4];
  #pragma unroll
  for (int s = 0; s < 4; ++s)
    qf[s] = *reinterpret_cast<const bf16x8*>(&Qh[(size_t)qg * D_ + s * 16 + hi * 8]);

  // per-lane fragment base pointers
  const unsigned short* Krow  = Kh + (size_t)q31 * D_ + hi * 8;         // + kv0*D_ per tile
  const unsigned short* VrowA = Vh + (size_t)q31 * T_ + hi * 8;         // d = q31
  const unsigned short* VrowB = Vh + (size_t)(32 + q31) * T_ + hi * 8;  // d = 32+q31

  float mrun = NEG_BIG, lrun = 0.f;
  f32x16 y0 = {}, y1 = {};

  const int nt = ((q0 + 31) >> 6) + 1;  // kv tiles 0..floor((q0+31)/64)

  // K fragment double buffer: [s] = row q31 + (s>>2)*32, k-slice (s&3)*16 + hi*8
  bf16x8 kfA[8], kfB[8];
  #pragma unroll
  for (int s = 0; s < 8; ++s)
    kfA[s] = *reinterpret_cast<const bf16x8*>(Krow + (size_t)(s >> 2) * 32 * D_ + (s & 3) * 16);

  auto tile_step = [&](bf16x8 (&kfc)[8], bf16x8 (&kfn)[8], int it) {
    const int kv0 = it << 6;

    // ---- V fragments for current tile (consumed after softmax)
    bf16x8 vfA[4], vfB[4];
    #pragma unroll
    for (int ks = 0; ks < 4; ++ks) {
      vfA[ks] = *reinterpret_cast<const bf16x8*>(VrowA + kv0 + ks * 16);
      vfB[ks] = *reinterpret_cast<const bf16x8*>(VrowB + kv0 + ks * 16);
    }

    // ---- K prefetch for NEXT tile (unconditional; last-iter overread stays in ws)
    const unsigned short* kN = Krow + (size_t)(kv0 + 64) * D_;
    #pragma unroll
    for (int s = 0; s < 8; ++s)
      kfn[s] = *reinterpret_cast<const bf16x8*>(kN + (size_t)(s >> 2) * 32 * D_ + (s & 3) * 16);

    // ---- S^T = K * Q^T : two 32x32 half-tiles (kv 0..31, 32..63)
    f32x16 s0 = {}, s1 = {};
    #pragma unroll
    for (int s = 0; s < 4; ++s)
      s0 = __builtin_amdgcn_mfma_f32_32x32x16_bf16(kfc[s], qf[s], s0, 0, 0, 0);
    #pragma unroll
    for (int s = 0; s < 4; ++s)
      s1 = __builtin_amdgcn_mfma_f32_32x32x16_bf16(kfc[4 + s], qf[s], s1, 0, 0, 0);

    // ---- causal mask (finite sentinel); kv_local = (r&3)+8*(r>>2)+4*hi
    if (kv0 + 63 > q0) {
      #pragma unroll
      for (int r = 0; r < 16; ++r) {
        const int kvl = (r & 3) + 8 * (r >> 2) + 4 * hi;
        s0[r] = (kv0 + kvl > qg)      ? NEG_BIG : s0[r];
        s1[r] = (kv0 + 32 + kvl > qg) ? NEG_BIG : s1[r];
      }
    }

    // ---- column max: in-lane tree + cross-half merge (shfl_xor 32)
    float a[16];
    #pragma unroll
    for (int r = 0; r < 8; ++r) a[r] = fmaxf(s0[2 * r], s0[2 * r + 1]);
    #pragma unroll
    for (int r = 0; r < 8; ++r) a[8 + r] = fmaxf(s1[2 * r], s1[2 * r + 1]);
    #pragma unroll
    for (int st = 8; st > 0; st >>= 1)
      #pragma unroll
      for (int r = 0; r < 16; ++r) if (r < st) a[r] = fmaxf(a[r], a[r + st]);
    float tmax = a[0];
    tmax = fmaxf(tmax, __shfl_xor(tmax, 32));

    // ---- online rescale (every tile; lane-local)
    const float mnew = fmaxf(mrun, tmax);
    const float alpha = __expf(mrun - mnew);  // exp(-1e30) = 0 on first tile
    mrun = mnew;
    lrun *= alpha;
    #pragma unroll
    for (int r = 0; r < 16; ++r) { y0[r] *= alpha; y1[r] *= alpha; }

    // ---- P = exp(S - m)
    #pragma unroll
    for (int r = 0; r < 16; ++r) {
      s0[r] = __expf(s0[r] - mrun);
      s1[r] = __expf(s1[r] - mrun);
    }

    // ---- column sum: tree + merge
    #pragma unroll
    for (int r = 0; r < 8; ++r) a[r] = s0[2 * r] + s0[2 * r + 1];
    #pragma unroll
    for (int r = 0; r < 8; ++r) a[8 + r] = s1[2 * r] + s1[2 * r + 1];
    #pragma unroll
    for (int st = 8; st > 0; st >>= 1)
      #pragma unroll
      for (int r = 0; r < 16; ++r) if (r < st) a[r] = a[r] + a[r + st];
    float rsum = a[0];
    rsum += __shfl_xor(rsum, 32);
    lrun += rsum;

    // ---- P^T B-fragments via pk2bf + shfl_xor(32) + select
    bf16x8 pf[4];
#define MK_PF(KS, SH, GA, HA)                                                 \
    {                                                                         \
      uint32_t g0 = pk2bf(SH[(GA)*4 + 0], SH[(GA)*4 + 1]);                    \
      uint32_t g1 = pk2bf(SH[(GA)*4 + 2], SH[(GA)*4 + 3]);                    \
      uint32_t h0 = pk2bf(SH[(HA)*4 + 0], SH[(HA)*4 + 1]);                    \
      uint32_t h1 = pk2bf(SH[(HA)*4 + 2], SH[(HA)*4 + 3]);                    \
      uint32_t sg0 = (uint32_t)__shfl_xor((int)g0, 32);                       \
      uint32_t sg1 = (uint32_t)__shfl_xor((int)g1, 32);                       \
      uint32_t sh0 = (uint32_t)__shfl_xor((int)h0, 32);                       \
      uint32_t sh1 = (uint32_t)__shfl_xor((int)h1, 32);                       \
      u32x4 t;                                                                \
      t[0] = hi ? sh0 : g0;                                                   \
      t[1] = hi ? sh1 : g1;                                                   \
      t[2] = hi ? h0 : sg0;                                                   \
      t[3] = hi ? h1 : sg1;                                                   \
      pf[KS] = __builtin_bit_cast(bf16x8, t);                                 \
    }
    MK_PF(0, s0, 0, 1)
    MK_PF(1, s0, 2, 3)
    MK_PF(2, s1, 0, 1)
    MK_PF(3, s1, 2, 3)
#undef MK_PF

    // ---- PV: Y^T += V^T * P^T  (A = V^T frag rows d / d+32, B = pf)
    #pragma unroll
    for (int ks = 0; ks < 4; ++ks)
      y0 = __builtin_amdgcn_mfma_f32_32x32x16_bf16(vfA[ks], pf[ks], y0, 0, 0, 0);
    #pragma unroll
    for (int ks = 0; ks < 4; ++ks)
      y1 = __builtin_amdgcn_mfma_f32_32x32x16_bf16(vfB[ks], pf[ks], y1, 0, 0, 0);
  };

  for (int it = 0; it < nt; ) {
    tile_step(kfA, kfB, it);
    ++it;
    if (it >= nt) break;
    tile_step(kfB, kfA, it);
    ++it;
  }

  // ---- epilogue: y/l, store row qg (lane-local). y reg r -> d = (r&3)+8*(r>>2)+4*hi
  const float inv = 1.f / lrun;
  const size_t ro = ((size_t)bb * T_ + qg) * C_ + hh * D_;
  #pragma unroll
  for (int q2 = 0; q2 < 4; ++q2) {
    {
      uint32_t w0 = pk2bf(y0[q2 * 4 + 0] * inv, y0[q2 * 4 + 1] * inv);
      uint32_t w1 = pk2bf(y0[q2 * 4 + 2] * inv, y0[q2 * 4 + 3] * inv);
      uint2 pr = {w0, w1};
      *reinterpret_cast<uint2*>(&Yb[ro + q2 * 8 + hi * 4]) = pr;
    }
    {
      uint32_t w0 = pk2bf(y1[q2 * 4 + 0] * inv, y1[q2 * 4 + 1] * inv);
      uint32_t w1 = pk2bf(y1[q2 * 4 + 2] * inv, y1[q2 * 4 + 3] * inv);
      uint2 pr = {w0, w1};
      *reinterpret_cast<uint2*>(&Yb[ro + 32 + q2 * 8 + hi * 4]) = pr;
    }
  }
}

// ---------------------------------------------------------------- launch
extern "C" void kernel_launch(void* const* d_in, const int* in_sizes, int n_in,
                              void* d_out, int out_size, void* d_ws, size_t ws_size,
                              hipStream_t stream) {
  const float* x      = (const float*)d_in[0];
  const float* w_attn = (const float*)d_in[1];
  const float* b_attn = (const float*)d_in[2];
  const float* w_proj = (const float*)d_in[3];
  const float* b_proj = (const float*)d_in[4];
  float* out = (float*)d_out;

  char* ws = (char*)d_ws;
  size_t off = 0;
  auto alloc = [&](size_t bytes) -> void* {
    void* p = ws + off;
    off += (bytes + 255) & ~(size_t)255;
    return p;
  };
  unsigned short* xb  = (unsigned short*)alloc((size_t)M_ * K_ * 2);       // x bf16
  unsigned short* waT = (unsigned short*)alloc((size_t)N1_ * K_ * 2);      // w_attn^T bf16
  unsigned short* wpT = (unsigned short*)alloc((size_t)C_ * K_ * 2);       // w_proj^T bf16
  unsigned short* Qb  = (unsigned short*)alloc((size_t)BH_ * T_ * D_ * 2); // [BH][T][D]
  unsigned short* Kb  = (unsigned short*)alloc((size_t)BH_ * T_ * D_ * 2);
  unsigned short* Vt  = (unsigned short*)alloc((size_t)BH_ * D_ * T_ * 2); // [BH][D][T]
  unsigned short* Yb  = (unsigned short*)alloc((size_t)M_ * C_ * 2);       // attn out bf16

  cast_kernel<<<1024, 256, 0, stream>>>(x, xb, M_ * K_ / 4);
  transpose_cast<<<dim3(N1_ / 32, K_ / 32), dim3(32, 8), 0, stream>>>(w_attn, waT, K_, N1_);
  transpose_cast<<<dim3(C_ / 32, K_ / 32), dim3(32, 8), 0, stream>>>(w_proj, wpT, K_, C_);

  gemm_kernel<0><<<dim3(M_ / 128, N1_ / 128), 256, 0, stream>>>(
      xb, waT, b_attn, Qb, Kb, Vt, nullptr);

  attn_kernel<<<(T_ / 32) * BH_, 64, 0, stream>>>(Qb, Kb, Vt, Yb);

  gemm_kernel<1><<<dim3(M_ / 128, C_ / 128), 256, 0, stream>>>(
      Yb, wpT, b_proj, nullptr, nullptr, nullptr, out);
}

// Round 8
// 205.404 us; speedup vs baseline: 1.7177x; 1.3539x over previous
//
#include <hip/hip_runtime.h>
#include <stdint.h>

// Problem constants
#define B_   2
#define T_   4096
#define C_   768
#define H_   12
#define D_   64
#define BH_  24      // B_*H_
#define M_   8192    // B_*T_
#define K_   768
#define N1_  2304    // 3*C_

#define NEG_BIG (-1.0e30f)

typedef short bf16x8 __attribute__((ext_vector_type(8)));
typedef float f32x4  __attribute__((ext_vector_type(4)));
typedef float f32x16 __attribute__((ext_vector_type(16)));
typedef uint32_t u32x4 __attribute__((ext_vector_type(4)));

typedef const __attribute__((address_space(1))) void* as1cv;
typedef __attribute__((address_space(3))) void*       as3v;

__device__ __forceinline__ void gload_lds16(const void* g, void* l) {
  __builtin_amdgcn_global_load_lds((as1cv)g, (as3v)l, 16, 0, 0);
}

// fp32 -> bf16 bits, round-to-nearest-even.
// NOTE: v_cvt_pk_bf16_f32 inline-asm is POISONED on this toolchain (R2: NaN,
// R6: absmax 7.4e30). Use this software path.
__device__ __forceinline__ unsigned short f2bf(float f) {
  uint32_t x = __builtin_bit_cast(uint32_t, f);
  uint32_t r = (x + 0x7fffu + ((x >> 16) & 1u)) >> 16;
  return (unsigned short)r;
}

__device__ __forceinline__ uint32_t pk2bf(float lo, float hi) {
  return ((uint32_t)f2bf(hi) << 16) | (uint32_t)f2bf(lo);
}

// ---------------------------------------------------------------- cast x -> bf16
__global__ void cast_kernel(const float* __restrict__ in, unsigned short* __restrict__ out, int n4) {
  int idx = blockIdx.x * blockDim.x + threadIdx.x;
  int stride = gridDim.x * blockDim.x;
  for (int i = idx; i < n4; i += stride) {
    float4 v = reinterpret_cast<const float4*>(in)[i];
    ushort4 o;
    o.x = f2bf(v.x); o.y = f2bf(v.y); o.z = f2bf(v.z); o.w = f2bf(v.w);
    reinterpret_cast<ushort4*>(out)[i] = o;
  }
}

// ------------------------------------------- transpose + cast: in[K][N] -> out[N][K] bf16
__global__ void transpose_cast(const float* __restrict__ in, unsigned short* __restrict__ out,
                               int K, int N) {
  __shared__ float tile[32][33];
  const int tx = threadIdx.x, ty = threadIdx.y;
  const int n = blockIdx.x * 32 + tx;
  #pragma unroll
  for (int r = 0; r < 4; ++r) {
    int k = blockIdx.y * 32 + ty + r * 8;
    tile[ty + r * 8][tx] = in[(size_t)k * N + n];
  }
  __syncthreads();
  const int k = blockIdx.y * 32 + tx;
  #pragma unroll
  for (int r = 0; r < 4; ++r) {
    int nn = blockIdx.x * 32 + ty + r * 8;
    out[(size_t)nn * K + k] = f2bf(tile[tx][ty + r * 8]);
  }
}

// ---------------------------------------------------------------- GEMM (m97-like)
// C[M][N] = A[M][768] * BT[N][768]^T + bias
// MODE 0: scatter epilogue -> Q [BH][T][D] (x0.125),
//         K in MFMA-tiled layout: [BH] + ((kv>>5)*4 + (k>>4))*512
//                                  + ((kv&31) + ((k>>3)&1)*32)*8 + (k&7)
//         V^T in MFMA-tiled layout: [BH] + (kv>>6)*4096 + (d>>5)*2048
//                                  + ((kv>>4)&3)*512 + ((d&31) + ((kv>>3)&1)*32)*8 + (kv&7)
//   (fragment loads in attn become base + lane*8 — fully coalesced 1KB bursts)
// MODE 1: plain fp32 store to fo[M][768]
template <int MODE>
__global__ __launch_bounds__(256) void gemm_kernel(
    const unsigned short* __restrict__ A, const unsigned short* __restrict__ BT,
    const float* __restrict__ bias,
    unsigned short* __restrict__ o0, unsigned short* __restrict__ o1,
    unsigned short* __restrict__ o2, float* __restrict__ fo) {
  __shared__ __align__(16) unsigned short Al[128 * 32];
  __shared__ __align__(16) unsigned short Bl[128 * 32];
  const int tid = threadIdx.x;
  const int w = tid >> 6, lane = tid & 63;
  const int g = lane >> 4, c16 = lane & 15;
  const int wr = w >> 1, wc = w & 1;
  const int m0 = blockIdx.x * 128, n0 = blockIdx.y * 128;

  f32x4 acc[4][4] = {};

  for (int k0 = 0; k0 < K_; k0 += 32) {
    __syncthreads();
    #pragma unroll
    for (int q = 0; q < 2; ++q) {
      const int ch = (w * 2 + q) * 64 + lane;     // 0..511
      const int row = ch >> 2, kb = ch & 3;       // 128 rows x 4 x 16B
      gload_lds16(A  + (size_t)(m0 + row) * K_ + k0 + kb * 8, &Al[(w * 2 + q) * 512]);
      gload_lds16(BT + (size_t)(n0 + row) * K_ + k0 + kb * 8, &Bl[(w * 2 + q) * 512]);
    }
    __syncthreads();
    bf16x8 af[4], bfr[4];
    #pragma unroll
    for (int i = 0; i < 4; ++i) {
      af[i]  = *reinterpret_cast<const bf16x8*>(&Al[(wr * 64 + i * 16 + c16) * 32 + g * 8]);
      bfr[i] = *reinterpret_cast<const bf16x8*>(&Bl[(wc * 64 + i * 16 + c16) * 32 + g * 8]);
    }
    #pragma unroll
    for (int i = 0; i < 4; ++i)
      #pragma unroll
      for (int j = 0; j < 4; ++j)
        acc[i][j] = __builtin_amdgcn_mfma_f32_16x16x32_bf16(af[i], bfr[j], acc[i][j], 0, 0, 0);
  }

  const int which = (MODE == 0) ? (n0 / 768) : 0;
  #pragma unroll
  for (int i = 0; i < 4; ++i) {
    const int mbase = m0 + wr * 64 + i * 16 + g * 4;
    #pragma unroll
    for (int j2 = 0; j2 < 4; ++j2) {
      const int n = n0 + wc * 64 + j2 * 16 + c16;
      const float bv = bias[n];
      #pragma unroll
      for (int j = 0; j < 4; ++j) {
        float v = acc[i][j2][j] + bv;
        const int mm = mbase + j;
        if constexpr (MODE == 0) {
          const int cc = n - which * 768;
          const int hh = cc >> 6, dd = cc & 63;
          const int bb = mm >> 12, tt = mm & 4095;   // tt = kv/time index
          const size_t bh = (size_t)bb * H_ + hh;
          const size_t hb = bh * T_ * D_;
          if (which == 0) {
            o0[hb + (size_t)tt * D_ + dd] = f2bf(v * 0.125f);   // Q pre-scaled
          } else if (which == 1) {
            // K tiled: kv=tt, k=dd
            const int addr = ((tt >> 5) * 4 + (dd >> 4)) * 512 +
                             ((tt & 31) + ((dd >> 3) & 1) * 32) * 8 + (dd & 7);
            o1[hb + addr] = f2bf(v);
          } else {
            // V^T tiled: d=dd, kv=tt
            const int addr = (tt >> 6) * 4096 + (dd >> 5) * 2048 +
                             ((tt >> 4) & 3) * 512 +
                             ((dd & 31) + ((tt >> 3) & 1) * 32) * 8 + (tt & 7);
            o2[hb + addr] = f2bf(v);
          }
        } else {
          fo[(size_t)mm * 768 + n] = v;
        }
      }
    }
  }
}

// ---------------------------------------------------------------- flash attention
// 1 wave per block, 32 q-rows, KVBLK=64, 32x32x16 MFMA, no LDS, no barriers.
// K and V^T live in MFMA-tiled layouts, so EVERY fragment load is a fully
// coalesced wave-load (base + lane*16B, one 1KB burst) — no 32-way gather.
// Depth-2 register pipeline: K fragments for tile t+1 prefetched into the
// alternate buffer while tile t computes. Swapped QK^T (mfma(K,Q) -> S^T):
// lane owns ONE q-row; softmax lane-local. P-pack via pk2bf + shfl_xor(32).
__global__ __launch_bounds__(64, 2) void attn_kernel(
    const unsigned short* __restrict__ Qb, const unsigned short* __restrict__ Kb,
    const unsigned short* __restrict__ Vt, unsigned short* __restrict__ Yb) {
  const int lane = threadIdx.x;
  const int q31 = lane & 31, hi = lane >> 5;
  const int bid = blockIdx.x;
  const int bh = bid % BH_;                     // bid%8 == bh%8 -> bh->XCD locality
  const int strip = (T_ / 32 - 1) - bid / BH_;  // 127..0, longest first
  const int q0 = strip * 32;
  const int qg = q0 + q31;  // this lane's q row

  const int bb = bh / H_, hh = bh % H_;
  const size_t hoff = (size_t)bh * T_ * D_;
  const unsigned short* Qh = Qb + hoff;
  const unsigned short* Kh = Kb + hoff + lane * 8;  // tiled: all frag loads + lane*8
  const unsigned short* Vh = Vt + hoff + lane * 8;

  // Q fragments: B-operand, col = q31, k = s*16 + hi*8 + e (one-time gather)
  bf16x8 qf[4];
  #pragma unroll
  for (int s = 0; s < 4; ++s)
    qf[s] = *reinterpret_cast<const bf16x8*>(&Qh[(size_t)qg * D_ + s * 16 + hi * 8]);

  float mrun = NEG_BIG, lrun = 0.f;
  f32x16 y0 = {}, y1 = {};

  const int nt = ((q0 + 31) >> 6) + 1;  // kv tiles 0..floor((q0+31)/64)

  // K fragment double buffer; tiled addr: kv0*64 + (s>>2)*2048 + (s&3)*512
  bf16x8 kfA[8], kfB[8];
  #pragma unroll
  for (int s = 0; s < 8; ++s)
    kfA[s] = *reinterpret_cast<const bf16x8*>(Kh + (s >> 2) * 2048 + (s & 3) * 512);

  auto tile_step = [&](bf16x8 (&kfc)[8], bf16x8 (&kfn)[8], int it) {
    const int kv0 = it << 6;

    // ---- V fragments for current tile (tiled: (kv0>>6)*4096 + half*2048 + ks*512)
    const unsigned short* vB = Vh + (kv0 >> 6) * 4096;
    bf16x8 vfA[4], vfB[4];
    #pragma unroll
    for (int ks = 0; ks < 4; ++ks) {
      vfA[ks] = *reinterpret_cast<const bf16x8*>(vB + ks * 512);
      vfB[ks] = *reinterpret_cast<const bf16x8*>(vB + 2048 + ks * 512);
    }

    // ---- K prefetch for NEXT tile (unconditional; tail over-read stays in ws)
    const unsigned short* kN = Kh + (kv0 + 64) * 64;
    #pragma unroll
    for (int s = 0; s < 8; ++s)
      kfn[s] = *reinterpret_cast<const bf16x8*>(kN + (s >> 2) * 2048 + (s & 3) * 512);

    // ---- S^T = K * Q^T : two 32x32 half-tiles (kv 0..31, 32..63)
    f32x16 s0 = {}, s1 = {};
    #pragma unroll
    for (int s = 0; s < 4; ++s)
      s0 = __builtin_amdgcn_mfma_f32_32x32x16_bf16(kfc[s], qf[s], s0, 0, 0, 0);
    #pragma unroll
    for (int s = 0; s < 4; ++s)
      s1 = __builtin_amdgcn_mfma_f32_32x32x16_bf16(kfc[4 + s], qf[s], s1, 0, 0, 0);

    // ---- causal mask (finite sentinel); kv_local = (r&3)+8*(r>>2)+4*hi
    if (kv0 + 63 > q0) {
      #pragma unroll
      for (int r = 0; r < 16; ++r) {
        const int kvl = (r & 3) + 8 * (r >> 2) + 4 * hi;
        s0[r] = (kv0 + kvl > qg)      ? NEG_BIG : s0[r];
        s1[r] = (kv0 + 32 + kvl > qg) ? NEG_BIG : s1[r];
      }
    }

    // ---- column max: in-lane tree + cross-half merge (shfl_xor 32)
    float a[16];
    #pragma unroll
    for (int r = 0; r < 8; ++r) a[r] = fmaxf(s0[2 * r], s0[2 * r + 1]);
    #pragma unroll
    for (int r = 0; r < 8; ++r) a[8 + r] = fmaxf(s1[2 * r], s1[2 * r + 1]);
    #pragma unroll
    for (int st = 8; st > 0; st >>= 1)
      #pragma unroll
      for (int r = 0; r < 16; ++r) if (r < st) a[r] = fmaxf(a[r], a[r + st]);
    float tmax = a[0];
    tmax = fmaxf(tmax, __shfl_xor(tmax, 32));

    // ---- online rescale (every tile; lane-local)
    const float mnew = fmaxf(mrun, tmax);
    const float alpha = __expf(mrun - mnew);  // exp(-1e30) = 0 on first tile
    mrun = mnew;
    lrun *= alpha;
    #pragma unroll
    for (int r = 0; r < 16; ++r) { y0[r] *= alpha; y1[r] *= alpha; }

    // ---- P = exp(S - m)
    #pragma unroll
    for (int r = 0; r < 16; ++r) {
      s0[r] = __expf(s0[r] - mrun);
      s1[r] = __expf(s1[r] - mrun);
    }

    // ---- column sum: tree + merge
    #pragma unroll
    for (int r = 0; r < 8; ++r) a[r] = s0[2 * r] + s0[2 * r + 1];
    #pragma unroll
    for (int r = 0; r < 8; ++r) a[8 + r] = s1[2 * r] + s1[2 * r + 1];
    #pragma unroll
    for (int st = 8; st > 0; st >>= 1)
      #pragma unroll
      for (int r = 0; r < 16; ++r) if (r < st) a[r] = a[r] + a[r + st];
    float rsum = a[0];
    rsum += __shfl_xor(rsum, 32);
    lrun += rsum;

    // ---- P^T B-fragments via pk2bf + shfl_xor(32) + select
    bf16x8 pf[4];
#define MK_PF(KS, SH, GA, HA)                                                 \
    {                                                                         \
      uint32_t g0 = pk2bf(SH[(GA)*4 + 0], SH[(GA)*4 + 1]);                    \
      uint32_t g1 = pk2bf(SH[(GA)*4 + 2], SH[(GA)*4 + 3]);                    \
      uint32_t h0 = pk2bf(SH[(HA)*4 + 0], SH[(HA)*4 + 1]);                    \
      uint32_t h1 = pk2bf(SH[(HA)*4 + 2], SH[(HA)*4 + 3]);                    \
      uint32_t sg0 = (uint32_t)__shfl_xor((int)g0, 32);                       \
      uint32_t sg1 = (uint32_t)__shfl_xor((int)g1, 32);                       \
      uint32_t sh0 = (uint32_t)__shfl_xor((int)h0, 32);                       \
      uint32_t sh1 = (uint32_t)__shfl_xor((int)h1, 32);                       \
      u32x4 t;                                                                \
      t[0] = hi ? sh0 : g0;                                                   \
      t[1] = hi ? sh1 : g1;                                                   \
      t[2] = hi ? h0 : sg0;                                                   \
      t[3] = hi ? h1 : sg1;                                                   \
      pf[KS] = __builtin_bit_cast(bf16x8, t);                                 \
    }
    MK_PF(0, s0, 0, 1)
    MK_PF(1, s0, 2, 3)
    MK_PF(2, s1, 0, 1)
    MK_PF(3, s1, 2, 3)
#undef MK_PF

    // ---- PV: Y^T += V^T * P^T  (A = V^T frag rows d / d+32, B = pf)
    #pragma unroll
    for (int ks = 0; ks < 4; ++ks)
      y0 = __builtin_amdgcn_mfma_f32_32x32x16_bf16(vfA[ks], pf[ks], y0, 0, 0, 0);
    #pragma unroll
    for (int ks = 0; ks < 4; ++ks)
      y1 = __builtin_amdgcn_mfma_f32_32x32x16_bf16(vfB[ks], pf[ks], y1, 0, 0, 0);
  };

  for (int it = 0; it < nt; ) {
    tile_step(kfA, kfB, it);
    ++it;
    if (it >= nt) break;
    tile_step(kfB, kfA, it);
    ++it;
  }

  // ---- epilogue: y/l, store row qg (lane-local). y reg r -> d = (r&3)+8*(r>>2)+4*hi
  const float inv = 1.f / lrun;
  const size_t ro = ((size_t)bb * T_ + qg) * C_ + hh * D_;
  #pragma unroll
  for (int q2 = 0; q2 < 4; ++q2) {
    {
      uint32_t w0 = pk2bf(y0[q2 * 4 + 0] * inv, y0[q2 * 4 + 1] * inv);
      uint32_t w1 = pk2bf(y0[q2 * 4 + 2] * inv, y0[q2 * 4 + 3] * inv);
      uint2 pr = {w0, w1};
      *reinterpret_cast<uint2*>(&Yb[ro + q2 * 8 + hi * 4]) = pr;
    }
    {
      uint32_t w0 = pk2bf(y1[q2 * 4 + 0] * inv, y1[q2 * 4 + 1] * inv);
      uint32_t w1 = pk2bf(y1[q2 * 4 + 2] * inv, y1[q2 * 4 + 3] * inv);
      uint2 pr = {w0, w1};
      *reinterpret_cast<uint2*>(&Yb[ro + 32 + q2 * 8 + hi * 4]) = pr;
    }
  }
}

// ---------------------------------------------------------------- launch
extern "C" void kernel_launch(void* const* d_in, const int* in_sizes, int n_in,
                              void* d_out, int out_size, void* d_ws, size_t ws_size,
                              hipStream_t stream) {
  const float* x      = (const float*)d_in[0];
  const float* w_attn = (const float*)d_in[1];
  const float* b_attn = (const float*)d_in[2];
  const float* w_proj = (const float*)d_in[3];
  const float* b_proj = (const float*)d_in[4];
  float* out = (float*)d_out;

  char* ws = (char*)d_ws;
  size_t off = 0;
  auto alloc = [&](size_t bytes) -> void* {
    void* p = ws + off;
    off += (bytes + 255) & ~(size_t)255;
    return p;
  };
  unsigned short* xb  = (unsigned short*)alloc((size_t)M_ * K_ * 2);       // x bf16
  unsigned short* waT = (unsigned short*)alloc((size_t)N1_ * K_ * 2);      // w_attn^T bf16
  unsigned short* wpT = (unsigned short*)alloc((size_t)C_ * K_ * 2);       // w_proj^T bf16
  unsigned short* Qb  = (unsigned short*)alloc((size_t)BH_ * T_ * D_ * 2); // [BH][T][D]
  unsigned short* Kb  = (unsigned short*)alloc((size_t)BH_ * T_ * D_ * 2); // tiled
  unsigned short* Vt  = (unsigned short*)alloc((size_t)BH_ * D_ * T_ * 2); // tiled
  unsigned short* Yb  = (unsigned short*)alloc((size_t)M_ * C_ * 2);       // attn out bf16

  cast_kernel<<<1024, 256, 0, stream>>>(x, xb, M_ * K_ / 4);
  transpose_cast<<<dim3(N1_ / 32, K_ / 32), dim3(32, 8), 0, stream>>>(w_attn, waT, K_, N1_);
  transpose_cast<<<dim3(C_ / 32, K_ / 32), dim3(32, 8), 0, stream>>>(w_proj, wpT, K_, C_);

  gemm_kernel<0><<<dim3(M_ / 128, N1_ / 128), 256, 0, stream>>>(
      xb, waT, b_attn, Qb, Kb, Vt, nullptr);

  attn_kernel<<<(T_ / 32) * BH_, 64, 0, stream>>>(Qb, Kb, Vt, Yb);

  gemm_kernel<1><<<dim3(M_ / 128, C_ / 128), 256, 0, stream>>>(
      Yb, wpT, b_proj, nullptr, nullptr, nullptr, out);
}

// Round 9
// 196.997 us; speedup vs baseline: 1.7910x; 1.0427x over previous
//
#include <hip/hip_runtime.h>
#include <stdint.h>

// Problem constants
#define B_   2
#define T_   4096
#define C_   768
#define H_   12
#define D_   64
#define BH_  24      // B_*H_
#define M_   8192    // B_*T_
#define K_   768
#define N1_  2304    // 3*C_

#define NEG_BIG (-1.0e30f)

typedef short bf16x8 __attribute__((ext_vector_type(8)));
typedef float f32x4  __attribute__((ext_vector_type(4)));
typedef float f32x16 __attribute__((ext_vector_type(16)));
typedef uint32_t u32x4 __attribute__((ext_vector_type(4)));
typedef int i32x2 __attribute__((ext_vector_type(2)));

typedef const __attribute__((address_space(1))) void* as1cv;
typedef __attribute__((address_space(3))) void*       as3v;

__device__ __forceinline__ void gload_lds16(const void* g, void* l) {
  __builtin_amdgcn_global_load_lds((as1cv)g, (as3v)l, 16, 0, 0);
}

// fp32 -> bf16 bits, round-to-nearest-even (prep kernels / GEMM epilogue).
// NOTE: v_cvt_pk_bf16_f32 inline-asm is POISONED on this toolchain (R2: NaN,
// R6: absmax 7.4e30). Software paths only.
__device__ __forceinline__ unsigned short f2bf(float f) {
  uint32_t x = __builtin_bit_cast(uint32_t, f);
  uint32_t r = (x + 0x7fffu + ((x >> 16) & 1u)) >> 16;
  return (unsigned short)r;
}

// cheap pack: round-half-up (away-from-zero on ties), 4 VALU ops total.
// Max error <= 0.5 ulp of bf16 — fine under the 4x absmax headroom.
__device__ __forceinline__ uint32_t pack_hu(float lo, float hi) {
  uint32_t a = __builtin_bit_cast(uint32_t, lo) + 0x8000u;
  uint32_t b = __builtin_bit_cast(uint32_t, hi) + 0x8000u;
  return (b & 0xFFFF0000u) | (a >> 16);
}

#if __has_builtin(__builtin_amdgcn_permlane32_swap)
#define HAVE_PLSWAP 1
#else
#define HAVE_PLSWAP 0
#endif

// ---------------------------------------------------------------- cast x -> bf16
__global__ void cast_kernel(const float* __restrict__ in, unsigned short* __restrict__ out, int n4) {
  int idx = blockIdx.x * blockDim.x + threadIdx.x;
  int stride = gridDim.x * blockDim.x;
  for (int i = idx; i < n4; i += stride) {
    float4 v = reinterpret_cast<const float4*>(in)[i];
    ushort4 o;
    o.x = f2bf(v.x); o.y = f2bf(v.y); o.z = f2bf(v.z); o.w = f2bf(v.w);
    reinterpret_cast<ushort4*>(out)[i] = o;
  }
}

// ------------------------------------------- transpose + cast: in[K][N] -> out[N][K] bf16
__global__ void transpose_cast(const float* __restrict__ in, unsigned short* __restrict__ out,
                               int K, int N) {
  __shared__ float tile[32][33];
  const int tx = threadIdx.x, ty = threadIdx.y;
  const int n = blockIdx.x * 32 + tx;
  #pragma unroll
  for (int r = 0; r < 4; ++r) {
    int k = blockIdx.y * 32 + ty + r * 8;
    tile[ty + r * 8][tx] = in[(size_t)k * N + n];
  }
  __syncthreads();
  const int k = blockIdx.y * 32 + tx;
  #pragma unroll
  for (int r = 0; r < 4; ++r) {
    int nn = blockIdx.x * 32 + ty + r * 8;
    out[(size_t)nn * K + k] = f2bf(tile[tx][ty + r * 8]);
  }
}

// ---------------------------------------------------------------- GEMM (m97-like)
// C[M][N] = A[M][768] * BT[N][768]^T + bias
// MODE 0: scatter epilogue -> Q [BH][T][D] (x0.125), K & V^T in MFMA-tiled
//         layouts (attn fragment loads become base + lane*16B bursts).
// MODE 1: plain fp32 store to fo[M][768]
template <int MODE>
__global__ __launch_bounds__(256) void gemm_kernel(
    const unsigned short* __restrict__ A, const unsigned short* __restrict__ BT,
    const float* __restrict__ bias,
    unsigned short* __restrict__ o0, unsigned short* __restrict__ o1,
    unsigned short* __restrict__ o2, float* __restrict__ fo) {
  __shared__ __align__(16) unsigned short Al[128 * 32];
  __shared__ __align__(16) unsigned short Bl[128 * 32];
  const int tid = threadIdx.x;
  const int w = tid >> 6, lane = tid & 63;
  const int g = lane >> 4, c16 = lane & 15;
  const int wr = w >> 1, wc = w & 1;
  const int m0 = blockIdx.x * 128, n0 = blockIdx.y * 128;

  f32x4 acc[4][4] = {};

  for (int k0 = 0; k0 < K_; k0 += 32) {
    __syncthreads();
    #pragma unroll
    for (int q = 0; q < 2; ++q) {
      const int ch = (w * 2 + q) * 64 + lane;     // 0..511
      const int row = ch >> 2, kb = ch & 3;       // 128 rows x 4 x 16B
      gload_lds16(A  + (size_t)(m0 + row) * K_ + k0 + kb * 8, &Al[(w * 2 + q) * 512]);
      gload_lds16(BT + (size_t)(n0 + row) * K_ + k0 + kb * 8, &Bl[(w * 2 + q) * 512]);
    }
    __syncthreads();
    bf16x8 af[4], bfr[4];
    #pragma unroll
    for (int i = 0; i < 4; ++i) {
      af[i]  = *reinterpret_cast<const bf16x8*>(&Al[(wr * 64 + i * 16 + c16) * 32 + g * 8]);
      bfr[i] = *reinterpret_cast<const bf16x8*>(&Bl[(wc * 64 + i * 16 + c16) * 32 + g * 8]);
    }
    #pragma unroll
    for (int i = 0; i < 4; ++i)
      #pragma unroll
      for (int j = 0; j < 4; ++j)
        acc[i][j] = __builtin_amdgcn_mfma_f32_16x16x32_bf16(af[i], bfr[j], acc[i][j], 0, 0, 0);
  }

  const int which = (MODE == 0) ? (n0 / 768) : 0;
  #pragma unroll
  for (int i = 0; i < 4; ++i) {
    const int mbase = m0 + wr * 64 + i * 16 + g * 4;
    #pragma unroll
    for (int j2 = 0; j2 < 4; ++j2) {
      const int n = n0 + wc * 64 + j2 * 16 + c16;
      const float bv = bias[n];
      #pragma unroll
      for (int j = 0; j < 4; ++j) {
        float v = acc[i][j2][j] + bv;
        const int mm = mbase + j;
        if constexpr (MODE == 0) {
          const int cc = n - which * 768;
          const int hh = cc >> 6, dd = cc & 63;
          const int bb = mm >> 12, tt = mm & 4095;   // tt = kv/time index
          const size_t bh = (size_t)bb * H_ + hh;
          const size_t hb = bh * T_ * D_;
          if (which == 0) {
            o0[hb + (size_t)tt * D_ + dd] = f2bf(v * 0.125f);   // Q pre-scaled
          } else if (which == 1) {
            // K tiled: kv=tt, k=dd
            const int addr = ((tt >> 5) * 4 + (dd >> 4)) * 512 +
                             ((tt & 31) + ((dd >> 3) & 1) * 32) * 8 + (dd & 7);
            o1[hb + addr] = f2bf(v);
          } else {
            // V^T tiled: d=dd, kv=tt
            const int addr = (tt >> 6) * 4096 + (dd >> 5) * 2048 +
                             ((tt >> 4) & 3) * 512 +
                             ((dd & 31) + ((tt >> 3) & 1) * 32) * 8 + (tt & 7);
            o2[hb + addr] = f2bf(v);
          }
        } else {
          fo[(size_t)mm * 768 + n] = v;
        }
      }
    }
  }
}

// ---------------------------------------------------------------- flash attention
// 1 wave per block, 32 q-rows, KVBLK=64, 32x32x16 MFMA, no LDS, no barriers.
// Tiled K/V layouts: every fragment load is base + lane*16B (coalesced burst).
// Depth-2 K register pipeline. Swapped QK^T: lane owns ONE q-row; softmax
// lane-local. VALU diet (R9): pack = round-half-up shift/or (4 ops/word),
// half-exchange via permlane32_swap builtin (T12), defer-max rescale (T13).
__global__ __launch_bounds__(64, 2) void attn_kernel(
    const unsigned short* __restrict__ Qb, const unsigned short* __restrict__ Kb,
    const unsigned short* __restrict__ Vt, unsigned short* __restrict__ Yb) {
  const int lane = threadIdx.x;
  const int q31 = lane & 31, hi = lane >> 5;
  const int bid = blockIdx.x;
  const int bh = bid % BH_;                     // bid%8 == bh%8 -> bh->XCD locality
  const int strip = (T_ / 32 - 1) - bid / BH_;  // 127..0, longest first
  const int q0 = strip * 32;
  const int qg = q0 + q31;  // this lane's q row

  const int bb = bh / H_, hh = bh % H_;
  const size_t hoff = (size_t)bh * T_ * D_;
  const unsigned short* Qh = Qb + hoff;
  const unsigned short* Kh = Kb + hoff + lane * 8;  // tiled: all frag loads + lane*8
  const unsigned short* Vh = Vt + hoff + lane * 8;

  // Q fragments: B-operand, col = q31, k = s*16 + hi*8 + e (one-time gather)
  bf16x8 qf[4];
  #pragma unroll
  for (int s = 0; s < 4; ++s)
    qf[s] = *reinterpret_cast<const bf16x8*>(&Qh[(size_t)qg * D_ + s * 16 + hi * 8]);

  float mrun = NEG_BIG, lrun = 0.f;
  f32x16 y0 = {}, y1 = {};

  const int nt = ((q0 + 31) >> 6) + 1;  // kv tiles 0..floor((q0+31)/64)

  // K fragment double buffer; tiled addr: kv0*64 + (s>>2)*2048 + (s&3)*512
  bf16x8 kfA[8], kfB[8];
  #pragma unroll
  for (int s = 0; s < 8; ++s)
    kfA[s] = *reinterpret_cast<const bf16x8*>(Kh + (s >> 2) * 2048 + (s & 3) * 512);

  auto tile_step = [&](bf16x8 (&kfc)[8], bf16x8 (&kfn)[8], int it) {
    const int kv0 = it << 6;

    // ---- V fragments for current tile (tiled: (kv0>>6)*4096 + half*2048 + ks*512)
    const unsigned short* vB = Vh + (kv0 >> 6) * 4096;
    bf16x8 vfA[4], vfB[4];
    #pragma unroll
    for (int ks = 0; ks < 4; ++ks) {
      vfA[ks] = *reinterpret_cast<const bf16x8*>(vB + ks * 512);
      vfB[ks] = *reinterpret_cast<const bf16x8*>(vB + 2048 + ks * 512);
    }

    // ---- K prefetch for NEXT tile (unconditional; tail over-read stays in ws)
    const unsigned short* kN = Kh + (kv0 + 64) * 64;
    #pragma unroll
    for (int s = 0; s < 8; ++s)
      kfn[s] = *reinterpret_cast<const bf16x8*>(kN + (s >> 2) * 2048 + (s & 3) * 512);

    // ---- S^T = K * Q^T : two 32x32 half-tiles (kv 0..31, 32..63)
    f32x16 s0 = {}, s1 = {};
    #pragma unroll
    for (int s = 0; s < 4; ++s)
      s0 = __builtin_amdgcn_mfma_f32_32x32x16_bf16(kfc[s], qf[s], s0, 0, 0, 0);
    #pragma unroll
    for (int s = 0; s < 4; ++s)
      s1 = __builtin_amdgcn_mfma_f32_32x32x16_bf16(kfc[4 + s], qf[s], s1, 0, 0, 0);

    // ---- causal mask (finite sentinel); kv_local = (r&3)+8*(r>>2)+4*hi
    if (kv0 + 63 > q0) {
      #pragma unroll
      for (int r = 0; r < 16; ++r) {
        const int kvl = (r & 3) + 8 * (r >> 2) + 4 * hi;
        s0[r] = (kv0 + kvl > qg)      ? NEG_BIG : s0[r];
        s1[r] = (kv0 + 32 + kvl > qg) ? NEG_BIG : s1[r];
      }
    }

    // ---- column max: in-lane tree + cross-half merge (shfl_xor 32)
    float a[16];
    #pragma unroll
    for (int r = 0; r < 8; ++r) a[r] = fmaxf(s0[2 * r], s0[2 * r + 1]);
    #pragma unroll
    for (int r = 0; r < 8; ++r) a[8 + r] = fmaxf(s1[2 * r], s1[2 * r + 1]);
    #pragma unroll
    for (int st = 8; st > 0; st >>= 1)
      #pragma unroll
      for (int r = 0; r < 16; ++r) if (r < st) a[r] = fmaxf(a[r], a[r + st]);
    float tmax = a[0];
    tmax = fmaxf(tmax, __shfl_xor(tmax, 32));

    // ---- defer-max rescale (T13, THR=8): skip O-rescale while max growth small
    if (__any(tmax > mrun + 8.f)) {
      const float mnew = fmaxf(mrun, tmax);
      const float alpha = __expf(mrun - mnew);  // exp(-1e30)=0 on first tile
      mrun = mnew;
      lrun *= alpha;
      #pragma unroll
      for (int r = 0; r < 16; ++r) { y0[r] *= alpha; y1[r] *= alpha; }
    }

    // ---- P = exp(S - m)  (bounded by e^8 under defer-max)
    #pragma unroll
    for (int r = 0; r < 16; ++r) {
      s0[r] = __expf(s0[r] - mrun);
      s1[r] = __expf(s1[r] - mrun);
    }

    // ---- column sum: tree + merge
    #pragma unroll
    for (int r = 0; r < 8; ++r) a[r] = s0[2 * r] + s0[2 * r + 1];
    #pragma unroll
    for (int r = 0; r < 8; ++r) a[8 + r] = s1[2 * r] + s1[2 * r + 1];
    #pragma unroll
    for (int st = 8; st > 0; st >>= 1)
      #pragma unroll
      for (int r = 0; r < 16; ++r) if (r < st) a[r] = a[r] + a[r + st];
    float rsum = a[0];
    rsum += __shfl_xor(rsum, 32);
    lrun += rsum;

    // ---- P^T B-fragments: cheap pack + permlane32_swap half-exchange.
    // swap(g,h): first = {g.row0, h.row0} = t0 ; second = {g.row1, h.row1} = t2.
    bf16x8 pf[4];
#if HAVE_PLSWAP
#define MK_PF(KS, SH, GA, HA)                                                 \
    {                                                                         \
      uint32_t g0 = pack_hu(SH[(GA)*4 + 0], SH[(GA)*4 + 1]);                  \
      uint32_t g1 = pack_hu(SH[(GA)*4 + 2], SH[(GA)*4 + 3]);                  \
      uint32_t h0 = pack_hu(SH[(HA)*4 + 0], SH[(HA)*4 + 1]);                  \
      uint32_t h1 = pack_hu(SH[(HA)*4 + 2], SH[(HA)*4 + 3]);                  \
      i32x2 r0 = __builtin_amdgcn_permlane32_swap((int)g0, (int)h0, false, false); \
      i32x2 r1 = __builtin_amdgcn_permlane32_swap((int)g1, (int)h1, false, false); \
      u32x4 t;                                                                \
      t[0] = (uint32_t)r0[0];                                                 \
      t[1] = (uint32_t)r1[0];                                                 \
      t[2] = (uint32_t)r0[1];                                                 \
      t[3] = (uint32_t)r1[1];                                                 \
      pf[KS] = __builtin_bit_cast(bf16x8, t);                                 \
    }
#else
#define MK_PF(KS, SH, GA, HA)                                                 \
    {                                                                         \
      uint32_t g0 = pack_hu(SH[(GA)*4 + 0], SH[(GA)*4 + 1]);                  \
      uint32_t g1 = pack_hu(SH[(GA)*4 + 2], SH[(GA)*4 + 3]);                  \
      uint32_t h0 = pack_hu(SH[(HA)*4 + 0], SH[(HA)*4 + 1]);                  \
      uint32_t h1 = pack_hu(SH[(HA)*4 + 2], SH[(HA)*4 + 3]);                  \
      uint32_t sg0 = (uint32_t)__shfl_xor((int)g0, 32);                       \
      uint32_t sg1 = (uint32_t)__shfl_xor((int)g1, 32);                       \
      uint32_t sh0 = (uint32_t)__shfl_xor((int)h0, 32);                       \
      uint32_t sh1 = (uint32_t)__shfl_xor((int)h1, 32);                       \
      u32x4 t;                                                                \
      t[0] = hi ? sh0 : g0;                                                   \
      t[1] = hi ? sh1 : g1;                                                   \
      t[2] = hi ? h0 : sg0;                                                   \
      t[3] = hi ? h1 : sg1;                                                   \
      pf[KS] = __builtin_bit_cast(bf16x8, t);                                 \
    }
#endif
    MK_PF(0, s0, 0, 1)
    MK_PF(1, s0, 2, 3)
    MK_PF(2, s1, 0, 1)
    MK_PF(3, s1, 2, 3)
#undef MK_PF

    // ---- PV: Y^T += V^T * P^T  (A = V^T frag rows d / d+32, B = pf)
    #pragma unroll
    for (int ks = 0; ks < 4; ++ks)
      y0 = __builtin_amdgcn_mfma_f32_32x32x16_bf16(vfA[ks], pf[ks], y0, 0, 0, 0);
    #pragma unroll
    for (int ks = 0; ks < 4; ++ks)
      y1 = __builtin_amdgcn_mfma_f32_32x32x16_bf16(vfB[ks], pf[ks], y1, 0, 0, 0);
  };

  for (int it = 0; it < nt; ) {
    tile_step(kfA, kfB, it);
    ++it;
    if (it >= nt) break;
    tile_step(kfB, kfA, it);
    ++it;
  }

  // ---- epilogue: y/l, store row qg (lane-local). y reg r -> d = (r&3)+8*(r>>2)+4*hi
  const float inv = 1.f / lrun;
  const size_t ro = ((size_t)bb * T_ + qg) * C_ + hh * D_;
  #pragma unroll
  for (int q2 = 0; q2 < 4; ++q2) {
    {
      uint32_t w0 = pack_hu(y0[q2 * 4 + 0] * inv, y0[q2 * 4 + 1] * inv);
      uint32_t w1 = pack_hu(y0[q2 * 4 + 2] * inv, y0[q2 * 4 + 3] * inv);
      uint2 pr = {w0, w1};
      *reinterpret_cast<uint2*>(&Yb[ro + q2 * 8 + hi * 4]) = pr;
    }
    {
      uint32_t w0 = pack_hu(y1[q2 * 4 + 0] * inv, y1[q2 * 4 + 1] * inv);
      uint32_t w1 = pack_hu(y1[q2 * 4 + 2] * inv, y1[q2 * 4 + 3] * inv);
      uint2 pr = {w0, w1};
      *reinterpret_cast<uint2*>(&Yb[ro + 32 + q2 * 8 + hi * 4]) = pr;
    }
  }
}

// ---------------------------------------------------------------- launch
extern "C" void kernel_launch(void* const* d_in, const int* in_sizes, int n_in,
                              void* d_out, int out_size, void* d_ws, size_t ws_size,
                              hipStream_t stream) {
  const float* x      = (const float*)d_in[0];
  const float* w_attn = (const float*)d_in[1];
  const float* b_attn = (const float*)d_in[2];
  const float* w_proj = (const float*)d_in[3];
  const float* b_proj = (const float*)d_in[4];
  float* out = (float*)d_out;

  char* ws = (char*)d_ws;
  size_t off = 0;
  auto alloc = [&](size_t bytes) -> void* {
    void* p = ws + off;
    off += (bytes + 255) & ~(size_t)255;
    return p;
  };
  unsigned short* xb  = (unsigned short*)alloc((size_t)M_ * K_ * 2);       // x bf16
  unsigned short* waT = (unsigned short*)alloc((size_t)N1_ * K_ * 2);      // w_attn^T bf16
  unsigned short* wpT = (unsigned short*)alloc((size_t)C_ * K_ * 2);       // w_proj^T bf16
  unsigned short* Qb  = (unsigned short*)alloc((size_t)BH_ * T_ * D_ * 2); // [BH][T][D]
  unsigned short* Kb  = (unsigned short*)alloc((size_t)BH_ * T_ * D_ * 2); // tiled
  unsigned short* Vt  = (unsigned short*)alloc((size_t)BH_ * D_ * T_ * 2); // tiled
  unsigned short* Yb  = (unsigned short*)alloc((size_t)M_ * C_ * 2);       // attn out bf16

  cast_kernel<<<1024, 256, 0, stream>>>(x, xb, M_ * K_ / 4);
  transpose_cast<<<dim3(N1_ / 32, K_ / 32), dim3(32, 8), 0, stream>>>(w_attn, waT, K_, N1_);
  transpose_cast<<<dim3(C_ / 32, K_ / 32), dim3(32, 8), 0, stream>>>(w_proj, wpT, K_, C_);

  gemm_kernel<0><<<dim3(M_ / 128, N1_ / 128), 256, 0, stream>>>(
      xb, waT, b_attn, Qb, Kb, Vt, nullptr);

  attn_kernel<<<(T_ / 32) * BH_, 64, 0, stream>>>(Qb, Kb, Vt, Yb);

  gemm_kernel<1><<<dim3(M_ / 128, C_ / 128), 256, 0, stream>>>(
      Yb, wpT, b_proj, nullptr, nullptr, nullptr, out);
}

// Round 10
// 186.285 us; speedup vs baseline: 1.8940x; 1.0575x over previous
//
#include <hip/hip_runtime.h>
#include <stdint.h>

// Problem constants
#define B_   2
#define T_   4096
#define C_   768
#define H_   12
#define D_   64
#define BH_  24      // B_*H_
#define M_   8192    // B_*T_
#define K_   768
#define N1_  2304    // 3*C_

#define NEG_BIG (-1.0e30f)

typedef short bf16x8 __attribute__((ext_vector_type(8)));
typedef float f32x4  __attribute__((ext_vector_type(4)));
typedef float f32x16 __attribute__((ext_vector_type(16)));
typedef uint32_t u32x4 __attribute__((ext_vector_type(4)));
typedef int i32x2 __attribute__((ext_vector_type(2)));

typedef const __attribute__((address_space(1))) void* as1cv;
typedef __attribute__((address_space(3))) void*       as3v;

__device__ __forceinline__ void gload_lds16(const void* g, void* l) {
  __builtin_amdgcn_global_load_lds((as1cv)g, (as3v)l, 16, 0, 0);
}

// fp32 -> bf16 bits, round-to-nearest-even (prep kernels / GEMM epilogue).
// NOTE: v_cvt_pk_bf16_f32 inline-asm is POISONED on this toolchain (R2: NaN,
// R6: absmax 7.4e30). Software paths only.
__device__ __forceinline__ unsigned short f2bf(float f) {
  uint32_t x = __builtin_bit_cast(uint32_t, f);
  uint32_t r = (x + 0x7fffu + ((x >> 16) & 1u)) >> 16;
  return (unsigned short)r;
}

// cheap pack: round-half-up, then byte-select the two hi-halves.
// v_perm_b32 path = 3 VALU ops; fallback = 5. Bit-identical results.
#if __has_builtin(__builtin_amdgcn_perm)
__device__ __forceinline__ uint32_t pack_hu(float lo, float hi) {
  uint32_t a = __builtin_bit_cast(uint32_t, lo) + 0x8000u;
  uint32_t b = __builtin_bit_cast(uint32_t, hi) + 0x8000u;
  // dst bytes = {a.b2, a.b3, b.b2, b.b3} -> sel 0x07060302 with src0=b, src1=a
  return __builtin_amdgcn_perm(b, a, 0x07060302u);
}
#else
__device__ __forceinline__ uint32_t pack_hu(float lo, float hi) {
  uint32_t a = __builtin_bit_cast(uint32_t, lo) + 0x8000u;
  uint32_t b = __builtin_bit_cast(uint32_t, hi) + 0x8000u;
  return (b & 0xFFFF0000u) | (a >> 16);
}
#endif

#if __has_builtin(__builtin_amdgcn_permlane32_swap)
#define HAVE_PLSWAP 1
#else
#define HAVE_PLSWAP 0
#endif

// ---------------------------------------------------------------- cast x -> bf16
__global__ void cast_kernel(const float* __restrict__ in, unsigned short* __restrict__ out, int n4) {
  int idx = blockIdx.x * blockDim.x + threadIdx.x;
  int stride = gridDim.x * blockDim.x;
  for (int i = idx; i < n4; i += stride) {
    float4 v = reinterpret_cast<const float4*>(in)[i];
    ushort4 o;
    o.x = f2bf(v.x); o.y = f2bf(v.y); o.z = f2bf(v.z); o.w = f2bf(v.w);
    reinterpret_cast<ushort4*>(out)[i] = o;
  }
}

// ------------------------------------------- transpose + cast: in[K][N] -> out[N][K] bf16
__global__ void transpose_cast(const float* __restrict__ in, unsigned short* __restrict__ out,
                               int K, int N) {
  __shared__ float tile[32][33];
  const int tx = threadIdx.x, ty = threadIdx.y;
  const int n = blockIdx.x * 32 + tx;
  #pragma unroll
  for (int r = 0; r < 4; ++r) {
    int k = blockIdx.y * 32 + ty + r * 8;
    tile[ty + r * 8][tx] = in[(size_t)k * N + n];
  }
  __syncthreads();
  const int k = blockIdx.y * 32 + tx;
  #pragma unroll
  for (int r = 0; r < 4; ++r) {
    int nn = blockIdx.x * 32 + ty + r * 8;
    out[(size_t)nn * K + k] = f2bf(tile[tx][ty + r * 8]);
  }
}

// ---------------------------------------------------------------- GEMM (m97-like)
// C[M][N] = A[M][768] * BT[N][768]^T + bias
// MODE 0: scatter epilogue -> Q [BH][T][D] (x0.125), K & V^T in MFMA-tiled
//         layouts (attn fragment loads become base + lane*16B bursts).
// MODE 1: plain fp32 store to fo[M][768]
template <int MODE>
__global__ __launch_bounds__(256) void gemm_kernel(
    const unsigned short* __restrict__ A, const unsigned short* __restrict__ BT,
    const float* __restrict__ bias,
    unsigned short* __restrict__ o0, unsigned short* __restrict__ o1,
    unsigned short* __restrict__ o2, float* __restrict__ fo) {
  __shared__ __align__(16) unsigned short Al[128 * 32];
  __shared__ __align__(16) unsigned short Bl[128 * 32];
  const int tid = threadIdx.x;
  const int w = tid >> 6, lane = tid & 63;
  const int g = lane >> 4, c16 = lane & 15;
  const int wr = w >> 1, wc = w & 1;
  const int m0 = blockIdx.x * 128, n0 = blockIdx.y * 128;

  f32x4 acc[4][4] = {};

  for (int k0 = 0; k0 < K_; k0 += 32) {
    __syncthreads();
    #pragma unroll
    for (int q = 0; q < 2; ++q) {
      const int ch = (w * 2 + q) * 64 + lane;     // 0..511
      const int row = ch >> 2, kb = ch & 3;       // 128 rows x 4 x 16B
      gload_lds16(A  + (size_t)(m0 + row) * K_ + k0 + kb * 8, &Al[(w * 2 + q) * 512]);
      gload_lds16(BT + (size_t)(n0 + row) * K_ + k0 + kb * 8, &Bl[(w * 2 + q) * 512]);
    }
    __syncthreads();
    bf16x8 af[4], bfr[4];
    #pragma unroll
    for (int i = 0; i < 4; ++i) {
      af[i]  = *reinterpret_cast<const bf16x8*>(&Al[(wr * 64 + i * 16 + c16) * 32 + g * 8]);
      bfr[i] = *reinterpret_cast<const bf16x8*>(&Bl[(wc * 64 + i * 16 + c16) * 32 + g * 8]);
    }
    #pragma unroll
    for (int i = 0; i < 4; ++i)
      #pragma unroll
      for (int j = 0; j < 4; ++j)
        acc[i][j] = __builtin_amdgcn_mfma_f32_16x16x32_bf16(af[i], bfr[j], acc[i][j], 0, 0, 0);
  }

  const int which = (MODE == 0) ? (n0 / 768) : 0;
  #pragma unroll
  for (int i = 0; i < 4; ++i) {
    const int mbase = m0 + wr * 64 + i * 16 + g * 4;
    #pragma unroll
    for (int j2 = 0; j2 < 4; ++j2) {
      const int n = n0 + wc * 64 + j2 * 16 + c16;
      const float bv = bias[n];
      #pragma unroll
      for (int j = 0; j < 4; ++j) {
        float v = acc[i][j2][j] + bv;
        const int mm = mbase + j;
        if constexpr (MODE == 0) {
          const int cc = n - which * 768;
          const int hh = cc >> 6, dd = cc & 63;
          const int bb = mm >> 12, tt = mm & 4095;   // tt = kv/time index
          const size_t bh = (size_t)bb * H_ + hh;
          const size_t hb = bh * T_ * D_;
          if (which == 0) {
            o0[hb + (size_t)tt * D_ + dd] = f2bf(v * 0.125f);   // Q pre-scaled
          } else if (which == 1) {
            // K tiled: kv=tt, k=dd
            const int addr = ((tt >> 5) * 4 + (dd >> 4)) * 512 +
                             ((tt & 31) + ((dd >> 3) & 1) * 32) * 8 + (dd & 7);
            o1[hb + addr] = f2bf(v);
          } else {
            // V^T tiled: d=dd, kv=tt
            const int addr = (tt >> 6) * 4096 + (dd >> 5) * 2048 +
                             ((tt >> 4) & 3) * 512 +
                             ((dd & 31) + ((tt >> 3) & 1) * 32) * 8 + (tt & 7);
            o2[hb + addr] = f2bf(v);
          }
        } else {
          fo[(size_t)mm * 768 + n] = v;
        }
      }
    }
  }
}

// ---------------------------------------------------------------- flash attention
// 2 waves per block, SAME 32 q-rows, kv tiles split round-robin (wave w takes
// tiles it ≡ w mod 2) — halves the serial causal tail (64 -> 32 tiles) and
// doubles resident waves. Each wave keeps private online-softmax state; wave1
// publishes (m,l,y) via LDS once; wave0 merges lane-elementwise and stores.
// Tiled K/V layouts: every fragment load is base + lane*16B (coalesced burst).
// Depth-2 K register pipeline per wave. Swapped QK^T: lane owns ONE q-row.
__global__ __launch_bounds__(128, 2) void attn_kernel(
    const unsigned short* __restrict__ Qb, const unsigned short* __restrict__ Kb,
    const unsigned short* __restrict__ Vt, unsigned short* __restrict__ Yb) {
  __shared__ float Ml[64];
  __shared__ float Ll[64];
  __shared__ __align__(16) float Yl[32][64];  // [reg][lane] — conflict-free

  const int tidx = threadIdx.x;
  const int wv = tidx >> 6;       // 0,1: kv-split partner index
  const int lane = tidx & 63;
  const int q31 = lane & 31, hi = lane >> 5;
  const int bid = blockIdx.x;
  const int bh = bid % BH_;                     // bid%8 == bh%8 -> bh->XCD locality
  const int strip = (T_ / 32 - 1) - bid / BH_;  // 127..0, longest first
  const int q0 = strip * 32;
  const int qg = q0 + q31;  // this lane's q row

  const int bb = bh / H_, hh = bh % H_;
  const size_t hoff = (size_t)bh * T_ * D_;
  const unsigned short* Qh = Qb + hoff;
  const unsigned short* Kh = Kb + hoff + lane * 8;  // tiled: all frag loads + lane*8
  const unsigned short* Vh = Vt + hoff + lane * 8;

  // Q fragments: B-operand, col = q31, k = s*16 + hi*8 + e (one-time gather)
  bf16x8 qf[4];
  #pragma unroll
  for (int s = 0; s < 4; ++s)
    qf[s] = *reinterpret_cast<const bf16x8*>(&Qh[(size_t)qg * D_ + s * 16 + hi * 8]);

  float mrun = NEG_BIG, lrun = 0.f;
  f32x16 y0 = {}, y1 = {};

  const int nt = ((q0 + 31) >> 6) + 1;  // kv tiles 0..floor((q0+31)/64)

  // K fragment double buffer; tiled addr: kv0*64 + (s>>2)*2048 + (s&3)*512
  bf16x8 kfA[8], kfB[8];

  auto tile_step = [&](bf16x8 (&kfc)[8], bf16x8 (&kfn)[8], int it) {
    const int kv0 = it << 6;

    // ---- V fragments for current tile (tiled: it*4096 + half*2048 + ks*512)
    const unsigned short* vB = Vh + it * 4096;
    bf16x8 vfA[4], vfB[4];
    #pragma unroll
    for (int ks = 0; ks < 4; ++ks) {
      vfA[ks] = *reinterpret_cast<const bf16x8*>(vB + ks * 512);
      vfB[ks] = *reinterpret_cast<const bf16x8*>(vB + 2048 + ks * 512);
    }

    // ---- K prefetch for MY next tile, it+2 (tail over-read stays in ws)
    const unsigned short* kN = Kh + it * 4096 + 8192;
    #pragma unroll
    for (int s = 0; s < 8; ++s)
      kfn[s] = *reinterpret_cast<const bf16x8*>(kN + (s >> 2) * 2048 + (s & 3) * 512);

    // ---- S^T = K * Q^T : two 32x32 half-tiles (kv 0..31, 32..63)
    f32x16 s0 = {}, s1 = {};
    #pragma unroll
    for (int s = 0; s < 4; ++s)
      s0 = __builtin_amdgcn_mfma_f32_32x32x16_bf16(kfc[s], qf[s], s0, 0, 0, 0);
    #pragma unroll
    for (int s = 0; s < 4; ++s)
      s1 = __builtin_amdgcn_mfma_f32_32x32x16_bf16(kfc[4 + s], qf[s], s1, 0, 0, 0);

    // ---- causal mask (finite sentinel); kv_local = (r&3)+8*(r>>2)+4*hi
    if (kv0 + 63 > q0) {
      #pragma unroll
      for (int r = 0; r < 16; ++r) {
        const int kvl = (r & 3) + 8 * (r >> 2) + 4 * hi;
        s0[r] = (kv0 + kvl > qg)      ? NEG_BIG : s0[r];
        s1[r] = (kv0 + 32 + kvl > qg) ? NEG_BIG : s1[r];
      }
    }

    // ---- column max: in-lane tree + cross-half merge (shfl_xor 32)
    float a[16];
    #pragma unroll
    for (int r = 0; r < 8; ++r) a[r] = fmaxf(s0[2 * r], s0[2 * r + 1]);
    #pragma unroll
    for (int r = 0; r < 8; ++r) a[8 + r] = fmaxf(s1[2 * r], s1[2 * r + 1]);
    #pragma unroll
    for (int st = 8; st > 0; st >>= 1)
      #pragma unroll
      for (int r = 0; r < 16; ++r) if (r < st) a[r] = fmaxf(a[r], a[r + st]);
    float tmax = a[0];
    tmax = fmaxf(tmax, __shfl_xor(tmax, 32));

    // ---- defer-max rescale (T13, THR=8): skip O-rescale while max growth small
    if (__any(tmax > mrun + 8.f)) {
      const float mnew = fmaxf(mrun, tmax);
      const float alpha = __expf(mrun - mnew);  // exp(-1e30)=0 on first tile
      mrun = mnew;
      lrun *= alpha;
      #pragma unroll
      for (int r = 0; r < 16; ++r) { y0[r] *= alpha; y1[r] *= alpha; }
    }

    // ---- P = exp(S - m)  (bounded by e^8 under defer-max)
    #pragma unroll
    for (int r = 0; r < 16; ++r) {
      s0[r] = __expf(s0[r] - mrun);
      s1[r] = __expf(s1[r] - mrun);
    }

    // ---- column sum: tree + merge
    #pragma unroll
    for (int r = 0; r < 8; ++r) a[r] = s0[2 * r] + s0[2 * r + 1];
    #pragma unroll
    for (int r = 0; r < 8; ++r) a[8 + r] = s1[2 * r] + s1[2 * r + 1];
    #pragma unroll
    for (int st = 8; st > 0; st >>= 1)
      #pragma unroll
      for (int r = 0; r < 16; ++r) if (r < st) a[r] = a[r] + a[r + st];
    float rsum = a[0];
    rsum += __shfl_xor(rsum, 32);
    lrun += rsum;

    // ---- P^T B-fragments: cheap pack + permlane32_swap half-exchange.
    bf16x8 pf[4];
#if HAVE_PLSWAP
#define MK_PF(KS, SH, GA, HA)                                                 \
    {                                                                         \
      uint32_t g0 = pack_hu(SH[(GA)*4 + 0], SH[(GA)*4 + 1]);                  \
      uint32_t g1 = pack_hu(SH[(GA)*4 + 2], SH[(GA)*4 + 3]);                  \
      uint32_t h0 = pack_hu(SH[(HA)*4 + 0], SH[(HA)*4 + 1]);                  \
      uint32_t h1 = pack_hu(SH[(HA)*4 + 2], SH[(HA)*4 + 3]);                  \
      i32x2 r0 = __builtin_amdgcn_permlane32_swap((int)g0, (int)h0, false, false); \
      i32x2 r1 = __builtin_amdgcn_permlane32_swap((int)g1, (int)h1, false, false); \
      u32x4 t;                                                                \
      t[0] = (uint32_t)r0[0];                                                 \
      t[1] = (uint32_t)r1[0];                                                 \
      t[2] = (uint32_t)r0[1];                                                 \
      t[3] = (uint32_t)r1[1];                                                 \
      pf[KS] = __builtin_bit_cast(bf16x8, t);                                 \
    }
#else
#define MK_PF(KS, SH, GA, HA)                                                 \
    {                                                                         \
      uint32_t g0 = pack_hu(SH[(GA)*4 + 0], SH[(GA)*4 + 1]);                  \
      uint32_t g1 = pack_hu(SH[(GA)*4 + 2], SH[(GA)*4 + 3]);                  \
      uint32_t h0 = pack_hu(SH[(HA)*4 + 0], SH[(HA)*4 + 1]);                  \
      uint32_t h1 = pack_hu(SH[(HA)*4 + 2], SH[(HA)*4 + 3]);                  \
      uint32_t sg0 = (uint32_t)__shfl_xor((int)g0, 32);                       \
      uint32_t sg1 = (uint32_t)__shfl_xor((int)g1, 32);                       \
      uint32_t sh0 = (uint32_t)__shfl_xor((int)h0, 32);                       \
      uint32_t sh1 = (uint32_t)__shfl_xor((int)h1, 32);                       \
      u32x4 t;                                                                \
      t[0] = hi ? sh0 : g0;                                                   \
      t[1] = hi ? sh1 : g1;                                                   \
      t[2] = hi ? h0 : sg0;                                                   \
      t[3] = hi ? h1 : sg1;                                                   \
      pf[KS] = __builtin_bit_cast(bf16x8, t);                                 \
    }
#endif
    MK_PF(0, s0, 0, 1)
    MK_PF(1, s0, 2, 3)
    MK_PF(2, s1, 0, 1)
    MK_PF(3, s1, 2, 3)
#undef MK_PF

    // ---- PV: Y^T += V^T * P^T  (A = V^T frag rows d / d+32, B = pf)
    #pragma unroll
    for (int ks = 0; ks < 4; ++ks)
      y0 = __builtin_amdgcn_mfma_f32_32x32x16_bf16(vfA[ks], pf[ks], y0, 0, 0, 0);
    #pragma unroll
    for (int ks = 0; ks < 4; ++ks)
      y1 = __builtin_amdgcn_mfma_f32_32x32x16_bf16(vfB[ks], pf[ks], y1, 0, 0, 0);
  };

  // my tiles: wv, wv+2, wv+4, ...
  int it = wv;
  if (it < nt) {
    #pragma unroll
    for (int s = 0; s < 8; ++s)
      kfA[s] = *reinterpret_cast<const bf16x8*>(
          Kh + (wv << 12) + (s >> 2) * 2048 + (s & 3) * 512);
    for (;;) {
      tile_step(kfA, kfB, it);
      it += 2; if (it >= nt) break;
      tile_step(kfB, kfA, it);
      it += 2; if (it >= nt) break;
    }
  }

  // ---- cross-wave merge: wave1 publishes, wave0 combines + stores
  if (wv == 1) {
    Ml[lane] = mrun;
    Ll[lane] = lrun;
    #pragma unroll
    for (int r = 0; r < 16; ++r) {
      Yl[r][lane] = y0[r];
      Yl[16 + r][lane] = y1[r];
    }
  }
  __syncthreads();
  if (wv == 0) {
    const float m1 = Ml[lane], l1 = Ll[lane];
    const float mm = fmaxf(mrun, m1);
    const float a0 = __expf(mrun - mm), a1 = __expf(m1 - mm);
    const float ll = lrun * a0 + l1 * a1;
    const float c0 = a0 / ll, c1 = a1 / ll;

    const size_t ro = ((size_t)bb * T_ + qg) * C_ + hh * D_;
    #pragma unroll
    for (int q2 = 0; q2 < 4; ++q2) {
      {
        float v0 = y0[q2 * 4 + 0] * c0 + Yl[q2 * 4 + 0][lane] * c1;
        float v1 = y0[q2 * 4 + 1] * c0 + Yl[q2 * 4 + 1][lane] * c1;
        float v2 = y0[q2 * 4 + 2] * c0 + Yl[q2 * 4 + 2][lane] * c1;
        float v3 = y0[q2 * 4 + 3] * c0 + Yl[q2 * 4 + 3][lane] * c1;
        uint2 pr = {pack_hu(v0, v1), pack_hu(v2, v3)};
        *reinterpret_cast<uint2*>(&Yb[ro + q2 * 8 + hi * 4]) = pr;
      }
      {
        float v0 = y1[q2 * 4 + 0] * c0 + Yl[16 + q2 * 4 + 0][lane] * c1;
        float v1 = y1[q2 * 4 + 1] * c0 + Yl[16 + q2 * 4 + 1][lane] * c1;
        float v2 = y1[q2 * 4 + 2] * c0 + Yl[16 + q2 * 4 + 2][lane] * c1;
        float v3 = y1[q2 * 4 + 3] * c0 + Yl[16 + q2 * 4 + 3][lane] * c1;
        uint2 pr = {pack_hu(v0, v1), pack_hu(v2, v3)};
        *reinterpret_cast<uint2*>(&Yb[ro + 32 + q2 * 8 + hi * 4]) = pr;
      }
    }
  }
}

// ---------------------------------------------------------------- launch
extern "C" void kernel_launch(void* const* d_in, const int* in_sizes, int n_in,
                              void* d_out, int out_size, void* d_ws, size_t ws_size,
                              hipStream_t stream) {
  const float* x      = (const float*)d_in[0];
  const float* w_attn = (const float*)d_in[1];
  const float* b_attn = (const float*)d_in[2];
  const float* w_proj = (const float*)d_in[3];
  const float* b_proj = (const float*)d_in[4];
  float* out = (float*)d_out;

  char* ws = (char*)d_ws;
  size_t off = 0;
  auto alloc = [&](size_t bytes) -> void* {
    void* p = ws + off;
    off += (bytes + 255) & ~(size_t)255;
    return p;
  };
  unsigned short* xb  = (unsigned short*)alloc((size_t)M_ * K_ * 2);       // x bf16
  unsigned short* waT = (unsigned short*)alloc((size_t)N1_ * K_ * 2);      // w_attn^T bf16
  unsigned short* wpT = (unsigned short*)alloc((size_t)C_ * K_ * 2);       // w_proj^T bf16
  unsigned short* Qb  = (unsigned short*)alloc((size_t)BH_ * T_ * D_ * 2); // [BH][T][D]
  unsigned short* Kb  = (unsigned short*)alloc((size_t)BH_ * T_ * D_ * 2); // tiled
  unsigned short* Vt  = (unsigned short*)alloc((size_t)BH_ * D_ * T_ * 2); // tiled
  unsigned short* Yb  = (unsigned short*)alloc((size_t)M_ * C_ * 2);       // attn out bf16

  cast_kernel<<<1024, 256, 0, stream>>>(x, xb, M_ * K_ / 4);
  transpose_cast<<<dim3(N1_ / 32, K_ / 32), dim3(32, 8), 0, stream>>>(w_attn, waT, K_, N1_);
  transpose_cast<<<dim3(C_ / 32, K_ / 32), dim3(32, 8), 0, stream>>>(w_proj, wpT, K_, C_);

  gemm_kernel<0><<<dim3(M_ / 128, N1_ / 128), 256, 0, stream>>>(
      xb, waT, b_attn, Qb, Kb, Vt, nullptr);

  attn_kernel<<<(T_ / 32) * BH_, 128, 0, stream>>>(Qb, Kb, Vt, Yb);

  gemm_kernel<1><<<dim3(M_ / 128, C_ / 128), 256, 0, stream>>>(
      Yb, wpT, b_proj, nullptr, nullptr, nullptr, out);
}